// Round 1
// baseline (1646.377 us; speedup 1.0000x reference)
//
#include <hip/hip_runtime.h>
#include <hip/hip_bf16.h>
#include <cstddef>
#include <cstdint>

#define B_N 2
#define L_N 2048
#define DM_N 1024
#define DS_N 16
#define DI_N 2048
#define NTOK (B_N * L_N)   // 4096
#define NPROJ 33           // 2*DS+1

// ---------------------------------------------------------------------------
// C[m,n] = sum_k A[m*K+k] * B[n*K+k]   (both operands K-major, "NT" GEMM)
// 128x128 tile, BK=16, 256 threads, 8x8 micro-tile per thread.
// ---------------------------------------------------------------------------
__global__ __launch_bounds__(256) void sgemm_nt_128(
    const float* __restrict__ A, const float* __restrict__ B,
    float* __restrict__ C, int M, int N, int K) {
  __shared__ float As[16][132];
  __shared__ float Bs[16][132];
  const int tid = threadIdx.x;
  const int tm = tid & 15;
  const int tn = tid >> 4;
  const int m0 = blockIdx.y * 128;
  const int n0 = blockIdx.x * 128;

  float acc[8][8];
#pragma unroll
  for (int i = 0; i < 8; ++i)
#pragma unroll
    for (int j = 0; j < 8; ++j) acc[i][j] = 0.f;

  const int lrow = tid >> 2;        // 0..63
  const int lk = (tid & 3) << 2;    // 0,4,8,12
  const float* Ap = A + (size_t)(m0 + lrow) * K + lk;
  const float* Bp = B + (size_t)(n0 + lrow) * K + lk;

  for (int kt = 0; kt < K; kt += 16) {
    float4 a0 = *(const float4*)Ap;
    float4 a1 = *(const float4*)(Ap + (size_t)64 * K);
    float4 b0 = *(const float4*)Bp;
    float4 b1 = *(const float4*)(Bp + (size_t)64 * K);
    Ap += 16; Bp += 16;
    __syncthreads();
    As[lk + 0][lrow] = a0.x; As[lk + 1][lrow] = a0.y;
    As[lk + 2][lrow] = a0.z; As[lk + 3][lrow] = a0.w;
    As[lk + 0][lrow + 64] = a1.x; As[lk + 1][lrow + 64] = a1.y;
    As[lk + 2][lrow + 64] = a1.z; As[lk + 3][lrow + 64] = a1.w;
    Bs[lk + 0][lrow] = b0.x; Bs[lk + 1][lrow] = b0.y;
    Bs[lk + 2][lrow] = b0.z; Bs[lk + 3][lrow] = b0.w;
    Bs[lk + 0][lrow + 64] = b1.x; Bs[lk + 1][lrow + 64] = b1.y;
    Bs[lk + 2][lrow + 64] = b1.z; Bs[lk + 3][lrow + 64] = b1.w;
    __syncthreads();
#pragma unroll
    for (int k = 0; k < 16; ++k) {
      float a[8], b[8];
      *(float4*)&a[0] = *(const float4*)&As[k][tm * 8];
      *(float4*)&a[4] = *(const float4*)&As[k][tm * 8 + 4];
      *(float4*)&b[0] = *(const float4*)&Bs[k][tn * 8];
      *(float4*)&b[4] = *(const float4*)&Bs[k][tn * 8 + 4];
#pragma unroll
      for (int i = 0; i < 8; ++i)
#pragma unroll
        for (int j = 0; j < 8; ++j) acc[i][j] = fmaf(a[i], b[j], acc[i][j]);
    }
  }

#pragma unroll
  for (int i = 0; i < 8; ++i) {
    float* Crow = C + (size_t)(m0 + tm * 8 + i) * N + n0 + tn * 8;
    float4 v0 = {acc[i][0], acc[i][1], acc[i][2], acc[i][3]};
    float4 v1 = {acc[i][4], acc[i][5], acc[i][6], acc[i][7]};
    *(float4*)Crow = v0;
    *(float4*)(Crow + 4) = v1;
  }
}

// ---------------------------------------------------------------------------
// Depthwise causal conv (DC=4) + bias, times silu(z). Reads xz = [u | z].
// u2[n,i] = (cb[i] + sum_j w[i,j]*u[n-3+j, i]) * silu(z[n,i])
// ---------------------------------------------------------------------------
__global__ __launch_bounds__(256) void conv_silu_kernel(
    const float* __restrict__ xz, const float* __restrict__ cw,
    const float* __restrict__ cb, float* __restrict__ u2) {
  size_t idx = (size_t)blockIdx.x * 256 + threadIdx.x;
  if (idx >= (size_t)NTOK * DI_N) return;
  int i = (int)(idx & (DI_N - 1));
  int n = (int)(idx >> 11);
  int l = n & (L_N - 1);
  const float* base = xz + (size_t)n * (2 * DI_N) + i;
  const float4 w = *(const float4*)&cw[i * 4];
  float acc = fmaf(w.w, base[0], cb[i]);
  if (l >= 1) acc = fmaf(w.z, base[-(ptrdiff_t)(2 * DI_N)], acc);
  if (l >= 2) acc = fmaf(w.y, base[-(ptrdiff_t)(4 * DI_N)], acc);
  if (l >= 3) acc = fmaf(w.x, base[-(ptrdiff_t)(6 * DI_N)], acc);
  float z = base[DI_N];
  float sil = z / (1.f + __expf(-z));
  u2[(size_t)n * DI_N + i] = acc * sil;
}

// ---------------------------------------------------------------------------
// proj[n,r] = sum_k u2[n,k] * xw[r,k], r < 33.  64 rows per block, KC=128.
// ---------------------------------------------------------------------------
__global__ __launch_bounds__(256) void xproj_kernel(
    const float* __restrict__ u2, const float* __restrict__ xw,
    float* __restrict__ proj) {
  __shared__ float uS[64][129];
  __shared__ float wS[36][128];
  const int tid = threadIdx.x;
  const int row0 = blockIdx.x * 64;
  const int crow = tid & 63;
  const int cg = tid >> 6;   // 0..3, cols cg*9 .. cg*9+8
  float acc[9];
#pragma unroll
  for (int j = 0; j < 9; ++j) acc[j] = 0.f;

  for (int kt = 0; kt < DI_N; kt += 128) {
    __syncthreads();
#pragma unroll
    for (int it = 0; it < 8; ++it) {
      int r = (tid >> 5) + it * 8;
      int kq = (tid & 31) << 2;
      float4 v = *(const float4*)&u2[(size_t)(row0 + r) * DI_N + kt + kq];
      uS[r][kq + 0] = v.x; uS[r][kq + 1] = v.y;
      uS[r][kq + 2] = v.z; uS[r][kq + 3] = v.w;
    }
    for (int s = tid; s < 36 * 128; s += 256) {
      int r = s >> 7, k = s & 127;
      wS[r][k] = (r < NPROJ) ? xw[(size_t)r * DI_N + kt + k] : 0.f;
    }
    __syncthreads();
#pragma unroll 4
    for (int k = 0; k < 128; ++k) {
      float uv = uS[crow][k];
#pragma unroll
      for (int j = 0; j < 9; ++j) acc[j] = fmaf(uv, wS[cg * 9 + j][k], acc[j]);
    }
  }
#pragma unroll
  for (int j = 0; j < 9; ++j) {
    int c = cg * 9 + j;
    if (c < NPROJ) proj[(size_t)(row0 + crow) * NPROJ + c] = acc[j];
  }
}

// ---------------------------------------------------------------------------
// Selective scan. thread = (b, i, s). 16 lanes (states) per channel.
// dte = exp(softplus(v)) = 1 + exp(v) exactly.
// ---------------------------------------------------------------------------
__global__ __launch_bounds__(256) void scan_kernel(
    const float* __restrict__ u2, const float* __restrict__ proj,
    const float* __restrict__ dtw, const float* __restrict__ dtb,
    const float* __restrict__ A_log, const float* __restrict__ Dp,
    float* __restrict__ y) {
  const int tid = threadIdx.x;
  const int s = tid & 15;
  const int ci = tid >> 4;              // 0..15
  const int b = blockIdx.x >> 7;        // 128 i-blocks per batch
  const int ib = blockIdx.x & 127;
  const int i = ib * 16 + ci;

  const float A = -__expf(A_log[i * DS_N + s]);
  const float w = dtw[i];
  const float bia = dtb[i];
  const float Dd = Dp[i];
  float h = 0.f;

  const float* un = u2 + (size_t)b * L_N * DI_N + i;
  const float* pr = proj + (size_t)b * L_N * NPROJ;
  float* yp = y + (size_t)b * L_N * DI_N + i;

  for (int l = 0; l < L_N; ++l) {
    float uv = un[(size_t)l * DI_N];
    float d0 = pr[l * NPROJ];
    float Bt = pr[l * NPROJ + 1 + s];
    float Ct = pr[l * NPROJ + 17 + s];
    float dte = 1.f + __expf(fmaf(d0, w, bia));
    float Ab = __expf(A * dte);
    h = fmaf(Ab, h, Bt * dte * uv);
    float p = h * Ct;
    p += __shfl_xor(p, 1, 64);
    p += __shfl_xor(p, 2, 64);
    p += __shfl_xor(p, 4, 64);
    p += __shfl_xor(p, 8, 64);
    if (s == 0) yp[(size_t)l * DI_N] = fmaf(Dd, uv, p);
  }
}

// ---------------------------------------------------------------------------
extern "C" void kernel_launch(void* const* d_in, const int* in_sizes, int n_in,
                              void* d_out, int out_size, void* d_ws, size_t ws_size,
                              hipStream_t stream) {
  const float* x          = (const float*)d_in[0];
  const float* in_proj_w  = (const float*)d_in[1];
  const float* conv_w     = (const float*)d_in[2];
  const float* conv_b     = (const float*)d_in[3];
  const float* x_proj_w   = (const float*)d_in[4];
  const float* dt_proj_w  = (const float*)d_in[5];
  const float* dt_proj_b  = (const float*)d_in[6];
  const float* A_log      = (const float*)d_in[7];
  const float* Dp         = (const float*)d_in[8];
  const float* out_proj_w = (const float*)d_in[9];
  float* out = (float*)d_out;

  char* ws = (char*)d_ws;
  float* xz   = (float*)ws;                                   // 4096*4096 f32 (67.1 MB)
  float* u2   = (float*)(ws + (size_t)NTOK * 2 * DI_N * 4);   // 4096*2048 f32 (33.5 MB)
  float* proj = (float*)(ws + (size_t)NTOK * 2 * DI_N * 4
                            + (size_t)NTOK * DI_N * 4);       // 4096*33 f32
  float* y = xz;  // xz dead after conv_silu; reuse for y

  // 1) xz = x @ in_proj_w.T : M=4096 N=4096 K=1024
  {
    dim3 g(4096 / 128, 4096 / 128);
    sgemm_nt_128<<<g, 256, 0, stream>>>(x, in_proj_w, xz, NTOK, 2 * DI_N, DM_N);
  }
  // 2) conv + silu
  {
    int nblk = (int)(((size_t)NTOK * DI_N + 255) / 256);
    conv_silu_kernel<<<nblk, 256, 0, stream>>>(xz, conv_w, conv_b, u2);
  }
  // 3) proj = u2 @ x_proj_w.T : N=33
  xproj_kernel<<<NTOK / 64, 256, 0, stream>>>(u2, x_proj_w, proj);
  // 4) selective scan -> y
  scan_kernel<<<B_N * (DI_N / 16), 256, 0, stream>>>(u2, proj, dt_proj_w,
                                                     dt_proj_b, A_log, Dp, y);
  // 5) out = y @ out_proj_w.T : M=4096 N=1024 K=2048
  {
    dim3 g(1024 / 128, 4096 / 128);
    sgemm_nt_128<<<g, 256, 0, stream>>>(y, out_proj_w, out, NTOK, DM_N, DI_N);
  }
}

// Round 2
// 1002.766 us; speedup vs baseline: 1.6418x; 1.6418x over previous
//
#include <hip/hip_runtime.h>
#include <hip/hip_bf16.h>
#include <cstddef>
#include <cstdint>

#define B_N 2
#define L_N 2048
#define DM_N 1024
#define DS_N 16
#define DI_N 2048
#define NTOK (B_N * L_N)   // 4096
#define NPROJ 33           // 2*DS+1
#define NC 32              // scan chunks
#define CL (L_N / NC)      // 64 steps per chunk

// ---------------------------------------------------------------------------
// C[m,n] = sum_k A[m*K+k] * B[n*K+k]   (both operands K-major, "NT" GEMM)
// 128x128 tile, BK=16, 256 threads, 8x8 micro-tile per thread.
// ---------------------------------------------------------------------------
__global__ __launch_bounds__(256) void sgemm_nt_128(
    const float* __restrict__ A, const float* __restrict__ B,
    float* __restrict__ C, int M, int N, int K) {
  __shared__ float As[16][132];
  __shared__ float Bs[16][132];
  const int tid = threadIdx.x;
  const int tm = tid & 15;
  const int tn = tid >> 4;
  const int m0 = blockIdx.y * 128;
  const int n0 = blockIdx.x * 128;

  float acc[8][8];
#pragma unroll
  for (int i = 0; i < 8; ++i)
#pragma unroll
    for (int j = 0; j < 8; ++j) acc[i][j] = 0.f;

  const int lrow = tid >> 2;        // 0..63
  const int lk = (tid & 3) << 2;    // 0,4,8,12
  const float* Ap = A + (size_t)(m0 + lrow) * K + lk;
  const float* Bp = B + (size_t)(n0 + lrow) * K + lk;

  for (int kt = 0; kt < K; kt += 16) {
    float4 a0 = *(const float4*)Ap;
    float4 a1 = *(const float4*)(Ap + (size_t)64 * K);
    float4 b0 = *(const float4*)Bp;
    float4 b1 = *(const float4*)(Bp + (size_t)64 * K);
    Ap += 16; Bp += 16;
    __syncthreads();
    As[lk + 0][lrow] = a0.x; As[lk + 1][lrow] = a0.y;
    As[lk + 2][lrow] = a0.z; As[lk + 3][lrow] = a0.w;
    As[lk + 0][lrow + 64] = a1.x; As[lk + 1][lrow + 64] = a1.y;
    As[lk + 2][lrow + 64] = a1.z; As[lk + 3][lrow + 64] = a1.w;
    Bs[lk + 0][lrow] = b0.x; Bs[lk + 1][lrow] = b0.y;
    Bs[lk + 2][lrow] = b0.z; Bs[lk + 3][lrow] = b0.w;
    Bs[lk + 0][lrow + 64] = b1.x; Bs[lk + 1][lrow + 64] = b1.y;
    Bs[lk + 2][lrow + 64] = b1.z; Bs[lk + 3][lrow + 64] = b1.w;
    __syncthreads();
#pragma unroll
    for (int k = 0; k < 16; ++k) {
      float a[8], b[8];
      *(float4*)&a[0] = *(const float4*)&As[k][tm * 8];
      *(float4*)&a[4] = *(const float4*)&As[k][tm * 8 + 4];
      *(float4*)&b[0] = *(const float4*)&Bs[k][tn * 8];
      *(float4*)&b[4] = *(const float4*)&Bs[k][tn * 8 + 4];
#pragma unroll
      for (int i = 0; i < 8; ++i)
#pragma unroll
        for (int j = 0; j < 8; ++j) acc[i][j] = fmaf(a[i], b[j], acc[i][j]);
    }
  }

#pragma unroll
  for (int i = 0; i < 8; ++i) {
    float* Crow = C + (size_t)(m0 + tm * 8 + i) * N + n0 + tn * 8;
    float4 v0 = {acc[i][0], acc[i][1], acc[i][2], acc[i][3]};
    float4 v1 = {acc[i][4], acc[i][5], acc[i][6], acc[i][7]};
    *(float4*)Crow = v0;
    *(float4*)(Crow + 4) = v1;
  }
}

// ---------------------------------------------------------------------------
// Depthwise causal conv (DC=4) + bias, times silu(z). Reads xz = [u | z].
// ---------------------------------------------------------------------------
__global__ __launch_bounds__(256) void conv_silu_kernel(
    const float* __restrict__ xz, const float* __restrict__ cw,
    const float* __restrict__ cb, float* __restrict__ u2) {
  size_t idx = (size_t)blockIdx.x * 256 + threadIdx.x;
  if (idx >= (size_t)NTOK * DI_N) return;
  int i = (int)(idx & (DI_N - 1));
  int n = (int)(idx >> 11);
  int l = n & (L_N - 1);
  const float* base = xz + (size_t)n * (2 * DI_N) + i;
  const float4 w = *(const float4*)&cw[i * 4];
  float acc = fmaf(w.w, base[0], cb[i]);
  if (l >= 1) acc = fmaf(w.z, base[-(ptrdiff_t)(2 * DI_N)], acc);
  if (l >= 2) acc = fmaf(w.y, base[-(ptrdiff_t)(4 * DI_N)], acc);
  if (l >= 3) acc = fmaf(w.x, base[-(ptrdiff_t)(6 * DI_N)], acc);
  float z = base[DI_N];
  float sil = z / (1.f + __expf(-z));
  u2[(size_t)n * DI_N + i] = acc * sil;
}

// ---------------------------------------------------------------------------
// proj[n,r] = sum_k u2[n,k] * xw[r,k], r < 33.
// ---------------------------------------------------------------------------
__global__ __launch_bounds__(256) void xproj_kernel(
    const float* __restrict__ u2, const float* __restrict__ xw,
    float* __restrict__ proj) {
  __shared__ float uS[64][129];
  __shared__ float wS[36][128];
  const int tid = threadIdx.x;
  const int row0 = blockIdx.x * 64;
  const int crow = tid & 63;
  const int cg = tid >> 6;
  float acc[9];
#pragma unroll
  for (int j = 0; j < 9; ++j) acc[j] = 0.f;

  for (int kt = 0; kt < DI_N; kt += 128) {
    __syncthreads();
#pragma unroll
    for (int it = 0; it < 8; ++it) {
      int r = (tid >> 5) + it * 8;
      int kq = (tid & 31) << 2;
      float4 v = *(const float4*)&u2[(size_t)(row0 + r) * DI_N + kt + kq];
      uS[r][kq + 0] = v.x; uS[r][kq + 1] = v.y;
      uS[r][kq + 2] = v.z; uS[r][kq + 3] = v.w;
    }
    for (int s = tid; s < 36 * 128; s += 256) {
      int r = s >> 7, k = s & 127;
      wS[r][k] = (r < NPROJ) ? xw[(size_t)r * DI_N + kt + k] : 0.f;
    }
    __syncthreads();
#pragma unroll 4
    for (int k = 0; k < 128; ++k) {
      float uv = uS[crow][k];
#pragma unroll
      for (int j = 0; j < 9; ++j) acc[j] = fmaf(uv, wS[cg * 9 + j][k], acc[j]);
    }
  }
#pragma unroll
  for (int j = 0; j < 9; ++j) {
    int c = cg * 9 + j;
    if (c < NPROJ) proj[(size_t)(row0 + crow) * NPROJ + c] = acc[j];
  }
}

// ---------------------------------------------------------------------------
// Chunked selective scan, pass 1: per (b,i,s,chunk) run recurrence from h=0,
// emit chunk-end state H and coefficient product P.
// carry layout: [c][b][i][s]  (index = (c*B + b)*DI*DS + i*DS + s)
// ---------------------------------------------------------------------------
__global__ __launch_bounds__(256) void scan_pass1_kernel(
    const float* __restrict__ u2, const float* __restrict__ proj,
    const float* __restrict__ dtw, const float* __restrict__ dtb,
    const float* __restrict__ A_log,
    float* __restrict__ carryH, float* __restrict__ carryP) {
  const int tid = threadIdx.x;
  const int s = tid & 15;
  const int ci = tid >> 4;
  const int bid = blockIdx.x;
  const int c = bid & (NC - 1);
  const int rest = bid >> 5;
  const int ib = rest & 127;
  const int b = rest >> 7;
  const int i = ib * 16 + ci;

  const float A = -__expf(A_log[i * DS_N + s]);
  const float w = dtw[i];
  const float bia = dtb[i];
  float h = 0.f, P = 1.f;

  const int l0 = c * CL;
  const float* un = u2 + ((size_t)b * L_N + l0) * DI_N + i;
  const float* pr = proj + ((size_t)b * L_N + l0) * NPROJ;

#pragma unroll 4
  for (int l = 0; l < CL; ++l) {
    float uv = un[(size_t)l * DI_N];
    float d0 = pr[l * NPROJ];
    float Bt = pr[l * NPROJ + 1 + s];
    float dte = 1.f + __expf(fmaf(d0, w, bia));
    float a = __expf(A * dte);
    h = fmaf(a, h, Bt * dte * uv);
    P *= a;
  }
  size_t cidx = ((size_t)c * B_N + b) * (DI_N * DS_N) + i * DS_N + s;
  carryH[cidx] = h;
  carryP[cidx] = P;
}

// ---------------------------------------------------------------------------
// Fixup: chain the NC chunk carries sequentially; overwrite carryH[c] with
// the INCOMING state h_in for chunk c.
// ---------------------------------------------------------------------------
__global__ __launch_bounds__(256) void scan_fixup_kernel(
    float* __restrict__ carryH, const float* __restrict__ carryP) {
  const int q = blockIdx.x * 256 + threadIdx.x;  // 0..B*DI*DS-1
  float h = 0.f;
#pragma unroll 4
  for (int c = 0; c < NC; ++c) {
    size_t idx = (size_t)c * (B_N * DI_N * DS_N) + q;
    float Hc = carryH[idx];
    float Pc = carryP[idx];
    carryH[idx] = h;
    h = fmaf(Pc, h, Hc);
  }
}

// ---------------------------------------------------------------------------
// Pass 2: re-run each chunk from its exact incoming state, emit y.
// ---------------------------------------------------------------------------
__global__ __launch_bounds__(256) void scan_pass2_kernel(
    const float* __restrict__ u2, const float* __restrict__ proj,
    const float* __restrict__ dtw, const float* __restrict__ dtb,
    const float* __restrict__ A_log, const float* __restrict__ Dp,
    const float* __restrict__ carryH, float* __restrict__ y) {
  const int tid = threadIdx.x;
  const int s = tid & 15;
  const int ci = tid >> 4;
  const int bid = blockIdx.x;
  const int c = bid & (NC - 1);
  const int rest = bid >> 5;
  const int ib = rest & 127;
  const int b = rest >> 7;
  const int i = ib * 16 + ci;

  const float A = -__expf(A_log[i * DS_N + s]);
  const float w = dtw[i];
  const float bia = dtb[i];
  const float Dd = Dp[i];
  float h = carryH[((size_t)c * B_N + b) * (DI_N * DS_N) + i * DS_N + s];

  const int l0 = c * CL;
  const float* un = u2 + ((size_t)b * L_N + l0) * DI_N + i;
  const float* pr = proj + ((size_t)b * L_N + l0) * NPROJ;
  float* yp = y + ((size_t)b * L_N + l0) * DI_N + i;

#pragma unroll 2
  for (int l = 0; l < CL; ++l) {
    float uv = un[(size_t)l * DI_N];
    float d0 = pr[l * NPROJ];
    float Bt = pr[l * NPROJ + 1 + s];
    float Ct = pr[l * NPROJ + 17 + s];
    float dte = 1.f + __expf(fmaf(d0, w, bia));
    float a = __expf(A * dte);
    h = fmaf(a, h, Bt * dte * uv);
    float p = h * Ct;
    p += __shfl_xor(p, 1, 64);
    p += __shfl_xor(p, 2, 64);
    p += __shfl_xor(p, 4, 64);
    p += __shfl_xor(p, 8, 64);
    if (s == 0) yp[(size_t)l * DI_N] = fmaf(Dd, uv, p);
  }
}

// ---------------------------------------------------------------------------
extern "C" void kernel_launch(void* const* d_in, const int* in_sizes, int n_in,
                              void* d_out, int out_size, void* d_ws, size_t ws_size,
                              hipStream_t stream) {
  const float* x          = (const float*)d_in[0];
  const float* in_proj_w  = (const float*)d_in[1];
  const float* conv_w     = (const float*)d_in[2];
  const float* conv_b     = (const float*)d_in[3];
  const float* x_proj_w   = (const float*)d_in[4];
  const float* dt_proj_w  = (const float*)d_in[5];
  const float* dt_proj_b  = (const float*)d_in[6];
  const float* A_log      = (const float*)d_in[7];
  const float* Dp         = (const float*)d_in[8];
  const float* out_proj_w = (const float*)d_in[9];
  float* out = (float*)d_out;

  char* ws = (char*)d_ws;
  float* xz   = (float*)ws;                                   // 4096*4096 f32 (67.1 MB)
  float* u2   = (float*)(ws + (size_t)NTOK * 2 * DI_N * 4);   // 4096*2048 f32 (33.5 MB)
  float* proj = (float*)(ws + (size_t)NTOK * 2 * DI_N * 4
                            + (size_t)NTOK * DI_N * 4);       // 4096*33 f32
  // xz is dead after conv_silu. Reuse: first 33.5MB for y, the rest for carries.
  float* y      = xz;
  float* carryH = xz + (size_t)NTOK * DI_N;                      // 2M f32 (8.4MB)
  float* carryP = carryH + (size_t)NC * B_N * DI_N * DS_N;       // 2M f32 (8.4MB)

  // 1) xz = x @ in_proj_w.T : M=4096 N=4096 K=1024
  {
    dim3 g(4096 / 128, 4096 / 128);
    sgemm_nt_128<<<g, 256, 0, stream>>>(x, in_proj_w, xz, NTOK, 2 * DI_N, DM_N);
  }
  // 2) conv + silu
  {
    int nblk = (int)(((size_t)NTOK * DI_N + 255) / 256);
    conv_silu_kernel<<<nblk, 256, 0, stream>>>(xz, conv_w, conv_b, u2);
  }
  // 3) proj = u2 @ x_proj_w.T : N=33
  xproj_kernel<<<NTOK / 64, 256, 0, stream>>>(u2, x_proj_w, proj);
  // 4) chunked selective scan -> y
  {
    int nblk = B_N * (DI_N / 16) * NC;  // 8192
    scan_pass1_kernel<<<nblk, 256, 0, stream>>>(u2, proj, dt_proj_w, dt_proj_b,
                                                A_log, carryH, carryP);
    scan_fixup_kernel<<<(B_N * DI_N * DS_N) / 256, 256, 0, stream>>>(carryH, carryP);
    scan_pass2_kernel<<<nblk, 256, 0, stream>>>(u2, proj, dt_proj_w, dt_proj_b,
                                                A_log, Dp, carryH, y);
  }
  // 5) out = y @ out_proj_w.T : M=4096 N=1024 K=2048
  {
    dim3 g(1024 / 128, 4096 / 128);
    sgemm_nt_128<<<g, 256, 0, stream>>>(y, out_proj_w, out, NTOK, DM_N, DI_N);
  }
}

// Round 3
// 845.805 us; speedup vs baseline: 1.9465x; 1.1856x over previous
//
#include <hip/hip_runtime.h>
#include <hip/hip_bf16.h>
#include <cstddef>
#include <cstdint>

#define B_N 2
#define L_N 2048
#define DM_N 1024
#define DS_N 16
#define DI_N 2048
#define NTOK (B_N * L_N)   // 4096
#define NPROJ 33           // 2*DS+1
#define NC 32              // scan chunks
#define CL (L_N / NC)      // 64 steps per chunk

typedef __attribute__((ext_vector_type(8))) short short8v;
typedef __attribute__((ext_vector_type(4))) float f32x4;
typedef __attribute__((address_space(1))) void av1;
typedef __attribute__((address_space(3))) void av3;

__device__ __forceinline__ void gload16(const void* g, void* l) {
  __builtin_amdgcn_global_load_lds((av1*)g, (av3*)l, 16, 0, 0);
}

__device__ __forceinline__ unsigned short f2bf_rn(float f) {
  uint32_t u = __float_as_uint(f);
  uint32_t r = (u + 0x7fffu + ((u >> 16) & 1u)) >> 16;
  return (unsigned short)r;
}

// ---------------------------------------------------------------------------
// Split fp32 -> (hi, lo) bf16 pair. 4 elements per thread.
// ---------------------------------------------------------------------------
__global__ __launch_bounds__(256) void split_bf16_kernel(
    const float* __restrict__ src, unsigned short* __restrict__ hi,
    unsigned short* __restrict__ lo, int n4) {
  int idx = blockIdx.x * 256 + threadIdx.x;
  if (idx >= n4) return;
  float4 v = ((const float4*)src)[idx];
  unsigned short h0 = f2bf_rn(v.x), h1 = f2bf_rn(v.y),
                 h2 = f2bf_rn(v.z), h3 = f2bf_rn(v.w);
  float f0 = __uint_as_float((uint32_t)h0 << 16);
  float f1 = __uint_as_float((uint32_t)h1 << 16);
  float f2 = __uint_as_float((uint32_t)h2 << 16);
  float f3 = __uint_as_float((uint32_t)h3 << 16);
  ushort4 hv = {h0, h1, h2, h3};
  ushort4 lv = {f2bf_rn(v.x - f0), f2bf_rn(v.y - f1),
                f2bf_rn(v.z - f2), f2bf_rn(v.w - f3)};
  ((ushort4*)hi)[idx] = hv;
  ((ushort4*)lo)[idx] = lv;
}

// ---------------------------------------------------------------------------
// Split-bf16 NT GEMM: C[m,n] = sum_k A[m,k]*B[n,k], A = Ah+Al, B = Bh+Bl.
// 128x128 tile, BK=32, 4 waves, 16x16x32 bf16 MFMA x3 per fragment.
// LDS layout per tile: [kgroup g=0..3][row 0..127] 16B slots (conflict-free).
// ---------------------------------------------------------------------------
__global__ __launch_bounds__(256) void gemm_bf16x3_nt(
    const unsigned short* __restrict__ Ah, const unsigned short* __restrict__ Al,
    const unsigned short* __restrict__ Bh, const unsigned short* __restrict__ Bl,
    float* __restrict__ C, int N, int K, int gx) {
  __shared__ __align__(16) unsigned short lds[4][4096];  // 4 tiles x 8KB
  const int tid = threadIdx.x;
  const int lane = tid & 63;
  const int wave = tid >> 6;

  // XCD-aware swizzle (grid size divisible by 8)
  const int nwg = gridDim.x;
  const int cpx = nwg >> 3;
  const int bid = blockIdx.x;
  const int wg = (bid & 7) * cpx + (bid >> 3);
  const int bx = wg % gx;
  const int by = wg / gx;
  const int m0 = by * 128, n0 = bx * 128;

  const int wr = wave >> 1, wc = wave & 1;

  // Staging: wave w stages tile w (0=Ah,1=Al,2=Bh,3=Bl), 8 chunks of 1KB.
  const unsigned short* gsrc[4] = {Ah, Al, Bh, Bl};
  const unsigned short* gbase = gsrc[wave];
  const int rowbase = (wave < 2) ? m0 : n0;
  const unsigned short* gptr[8];
#pragma unroll
  for (int c = 0; c < 8; ++c) {
    int slot = c * 64 + lane;
    int g = slot >> 7, r = slot & 127;
    gptr[c] = gbase + (size_t)(rowbase + r) * K + g * 8;
  }
  unsigned short* ldsbase = &lds[wave][0];

  f32x4 acc[4][4] = {};

  const int fr = lane & 15;
  const int fg = lane >> 4;
  const int arow0 = wr * 64 + fr;
  const int brow0 = wc * 64 + fr;

  for (int kt = 0; kt < K; kt += 32) {
#pragma unroll
    for (int c = 0; c < 8; ++c) {
      gload16(gptr[c] + kt, ldsbase + c * 512);
    }
    __syncthreads();

    short8v afh[4], afl[4], bfh[4], bfl[4];
#pragma unroll
    for (int m = 0; m < 4; ++m) {
      int idx = fg * 1024 + (arow0 + m * 16) * 8;
      afh[m] = *(const short8v*)&lds[0][idx];
      afl[m] = *(const short8v*)&lds[1][idx];
    }
#pragma unroll
    for (int n = 0; n < 4; ++n) {
      int idx = fg * 1024 + (brow0 + n * 16) * 8;
      bfh[n] = *(const short8v*)&lds[2][idx];
      bfl[n] = *(const short8v*)&lds[3][idx];
    }
#pragma unroll
    for (int m = 0; m < 4; ++m) {
#pragma unroll
      for (int n = 0; n < 4; ++n) {
        asm("v_mfma_f32_16x16x32_bf16 %0, %1, %2, %0"
            : "+v"(acc[m][n]) : "v"(afh[m]), "v"(bfh[n]));
        asm("v_mfma_f32_16x16x32_bf16 %0, %1, %2, %0"
            : "+v"(acc[m][n]) : "v"(afh[m]), "v"(bfl[n]));
        asm("v_mfma_f32_16x16x32_bf16 %0, %1, %2, %0"
            : "+v"(acc[m][n]) : "v"(afl[m]), "v"(bfh[n]));
      }
    }
    __syncthreads();
  }

#pragma unroll
  for (int m = 0; m < 4; ++m) {
#pragma unroll
    for (int n = 0; n < 4; ++n) {
#pragma unroll
      for (int q = 0; q < 4; ++q) {
        int row = m0 + wr * 64 + m * 16 + fg * 4 + q;
        int col = n0 + wc * 64 + n * 16 + fr;
        C[(size_t)row * N + col] = acc[m][n][q];
      }
    }
  }
}

// ---------------------------------------------------------------------------
// Depthwise causal conv (DC=4) + bias, times silu(z). Reads xz = [u | z].
// ---------------------------------------------------------------------------
__global__ __launch_bounds__(256) void conv_silu_kernel(
    const float* __restrict__ xz, const float* __restrict__ cw,
    const float* __restrict__ cb, float* __restrict__ u2) {
  size_t idx = (size_t)blockIdx.x * 256 + threadIdx.x;
  if (idx >= (size_t)NTOK * DI_N) return;
  int i = (int)(idx & (DI_N - 1));
  int n = (int)(idx >> 11);
  int l = n & (L_N - 1);
  const float* base = xz + (size_t)n * (2 * DI_N) + i;
  const float4 w = *(const float4*)&cw[i * 4];
  float acc = fmaf(w.w, base[0], cb[i]);
  if (l >= 1) acc = fmaf(w.z, base[-(ptrdiff_t)(2 * DI_N)], acc);
  if (l >= 2) acc = fmaf(w.y, base[-(ptrdiff_t)(4 * DI_N)], acc);
  if (l >= 3) acc = fmaf(w.x, base[-(ptrdiff_t)(6 * DI_N)], acc);
  float z = base[DI_N];
  float sil = z / (1.f + __expf(-z));
  u2[(size_t)n * DI_N + i] = acc * sil;
}

// ---------------------------------------------------------------------------
// proj[n,r] = sum_k u2[n,k] * xw[r,k], r < 33.
// ---------------------------------------------------------------------------
__global__ __launch_bounds__(256) void xproj_kernel(
    const float* __restrict__ u2, const float* __restrict__ xw,
    float* __restrict__ proj) {
  __shared__ float uS[64][129];
  __shared__ float wS[36][128];
  const int tid = threadIdx.x;
  const int row0 = blockIdx.x * 64;
  const int crow = tid & 63;
  const int cg = tid >> 6;
  float acc[9];
#pragma unroll
  for (int j = 0; j < 9; ++j) acc[j] = 0.f;

  for (int kt = 0; kt < DI_N; kt += 128) {
    __syncthreads();
#pragma unroll
    for (int it = 0; it < 8; ++it) {
      int r = (tid >> 5) + it * 8;
      int kq = (tid & 31) << 2;
      float4 v = *(const float4*)&u2[(size_t)(row0 + r) * DI_N + kt + kq];
      uS[r][kq + 0] = v.x; uS[r][kq + 1] = v.y;
      uS[r][kq + 2] = v.z; uS[r][kq + 3] = v.w;
    }
    for (int s = tid; s < 36 * 128; s += 256) {
      int r = s >> 7, k = s & 127;
      wS[r][k] = (r < NPROJ) ? xw[(size_t)r * DI_N + kt + k] : 0.f;
    }
    __syncthreads();
#pragma unroll 4
    for (int k = 0; k < 128; ++k) {
      float uv = uS[crow][k];
#pragma unroll
      for (int j = 0; j < 9; ++j) acc[j] = fmaf(uv, wS[cg * 9 + j][k], acc[j]);
    }
  }
#pragma unroll
  for (int j = 0; j < 9; ++j) {
    int c = cg * 9 + j;
    if (c < NPROJ) proj[(size_t)(row0 + crow) * NPROJ + c] = acc[j];
  }
}

// ---------------------------------------------------------------------------
// Chunked selective scan, pass 1: per (b,i,s,chunk) from h=0, emit H and P.
// ---------------------------------------------------------------------------
__global__ __launch_bounds__(256) void scan_pass1_kernel(
    const float* __restrict__ u2, const float* __restrict__ proj,
    const float* __restrict__ dtw, const float* __restrict__ dtb,
    const float* __restrict__ A_log,
    float* __restrict__ carryH, float* __restrict__ carryP) {
  const int tid = threadIdx.x;
  const int s = tid & 15;
  const int ci = tid >> 4;
  const int bid = blockIdx.x;
  const int c = bid & (NC - 1);
  const int rest = bid >> 5;
  const int ib = rest & 127;
  const int b = rest >> 7;
  const int i = ib * 16 + ci;

  const float A = -__expf(A_log[i * DS_N + s]);
  const float w = dtw[i];
  const float bia = dtb[i];
  float h = 0.f, P = 1.f;

  const int l0 = c * CL;
  const float* un = u2 + ((size_t)b * L_N + l0) * DI_N + i;
  const float* pr = proj + ((size_t)b * L_N + l0) * NPROJ;

#pragma unroll 4
  for (int l = 0; l < CL; ++l) {
    float uv = un[(size_t)l * DI_N];
    float d0 = pr[l * NPROJ];
    float Bt = pr[l * NPROJ + 1 + s];
    float dte = 1.f + __expf(fmaf(d0, w, bia));
    float a = __expf(A * dte);
    h = fmaf(a, h, Bt * dte * uv);
    P *= a;
  }
  size_t cidx = ((size_t)c * B_N + b) * (DI_N * DS_N) + i * DS_N + s;
  carryH[cidx] = h;
  carryP[cidx] = P;
}

// ---------------------------------------------------------------------------
// Fixup: chain chunk carries; carryH[c] <- incoming state for chunk c.
// ---------------------------------------------------------------------------
__global__ __launch_bounds__(256) void scan_fixup_kernel(
    float* __restrict__ carryH, const float* __restrict__ carryP) {
  const int q = blockIdx.x * 256 + threadIdx.x;
  float h = 0.f;
#pragma unroll 4
  for (int c = 0; c < NC; ++c) {
    size_t idx = (size_t)c * (B_N * DI_N * DS_N) + q;
    float Hc = carryH[idx];
    float Pc = carryP[idx];
    carryH[idx] = h;
    h = fmaf(Pc, h, Hc);
  }
}

// ---------------------------------------------------------------------------
// Pass 2: re-run chunks from exact carry; emit y directly as bf16 hi/lo.
// ---------------------------------------------------------------------------
__global__ __launch_bounds__(256) void scan_pass2_kernel(
    const float* __restrict__ u2, const float* __restrict__ proj,
    const float* __restrict__ dtw, const float* __restrict__ dtb,
    const float* __restrict__ A_log, const float* __restrict__ Dp,
    const float* __restrict__ carryH,
    unsigned short* __restrict__ yh, unsigned short* __restrict__ yl) {
  const int tid = threadIdx.x;
  const int s = tid & 15;
  const int ci = tid >> 4;
  const int bid = blockIdx.x;
  const int c = bid & (NC - 1);
  const int rest = bid >> 5;
  const int ib = rest & 127;
  const int b = rest >> 7;
  const int i = ib * 16 + ci;

  const float A = -__expf(A_log[i * DS_N + s]);
  const float w = dtw[i];
  const float bia = dtb[i];
  const float Dd = Dp[i];
  float h = carryH[((size_t)c * B_N + b) * (DI_N * DS_N) + i * DS_N + s];

  const int l0 = c * CL;
  const float* un = u2 + ((size_t)b * L_N + l0) * DI_N + i;
  const float* pr = proj + ((size_t)b * L_N + l0) * NPROJ;
  size_t ybase = ((size_t)b * L_N + l0) * DI_N + i;

#pragma unroll 2
  for (int l = 0; l < CL; ++l) {
    float uv = un[(size_t)l * DI_N];
    float d0 = pr[l * NPROJ];
    float Bt = pr[l * NPROJ + 1 + s];
    float Ct = pr[l * NPROJ + 17 + s];
    float dte = 1.f + __expf(fmaf(d0, w, bia));
    float a = __expf(A * dte);
    h = fmaf(a, h, Bt * dte * uv);
    float p = h * Ct;
    p += __shfl_xor(p, 1, 64);
    p += __shfl_xor(p, 2, 64);
    p += __shfl_xor(p, 4, 64);
    p += __shfl_xor(p, 8, 64);
    if (s == 0) {
      float yv = fmaf(Dd, uv, p);
      unsigned short hh = f2bf_rn(yv);
      float hf = __uint_as_float((uint32_t)hh << 16);
      yh[ybase + (size_t)l * DI_N] = hh;
      yl[ybase + (size_t)l * DI_N] = f2bf_rn(yv - hf);
    }
  }
}

// ---------------------------------------------------------------------------
extern "C" void kernel_launch(void* const* d_in, const int* in_sizes, int n_in,
                              void* d_out, int out_size, void* d_ws, size_t ws_size,
                              hipStream_t stream) {
  const float* x          = (const float*)d_in[0];
  const float* in_proj_w  = (const float*)d_in[1];
  const float* conv_w     = (const float*)d_in[2];
  const float* conv_b     = (const float*)d_in[3];
  const float* x_proj_w   = (const float*)d_in[4];
  const float* dt_proj_w  = (const float*)d_in[5];
  const float* dt_proj_b  = (const float*)d_in[6];
  const float* A_log      = (const float*)d_in[7];
  const float* Dp         = (const float*)d_in[8];
  const float* out_proj_w = (const float*)d_in[9];
  float* out = (float*)d_out;

  char* ws = (char*)d_ws;
  float* xz = (float*)ws;                                        // [0, 67.1MB)
  float* u2 = (float*)(ws + (size_t)NTOK * 2 * DI_N * 4);        // [67.1, 100.7)
  float* proj = (float*)(ws + (size_t)NTOK * 2 * DI_N * 4
                            + (size_t)NTOK * DI_N * 4);          // [100.7, 101.2)

  // conversion region = u2 region (dead until conv_silu runs)
  unsigned short* x_hi  = (unsigned short*)u2;
  unsigned short* x_lo  = x_hi + (size_t)NTOK * DM_N;
  unsigned short* w1_hi = x_lo + (size_t)NTOK * DM_N;
  unsigned short* w1_lo = w1_hi + (size_t)NTOK * DM_N;

  // xz region reuse after conv_silu
  unsigned short* y_hi = (unsigned short*)xz;                       // 16.78MB
  unsigned short* y_lo = y_hi + (size_t)NTOK * DI_N;                // 16.78MB
  float* carryH = (float*)(y_lo + (size_t)NTOK * DI_N);             // 8.39MB
  float* carryP = carryH + (size_t)NC * B_N * DI_N * DS_N;          // 8.39MB
  unsigned short* w2_hi = (unsigned short*)(carryP + (size_t)NC * B_N * DI_N * DS_N);
  unsigned short* w2_lo = w2_hi + (size_t)DM_N * DI_N;              // end 58.7MB

  // 1) split x and in_proj_w to bf16 hi/lo
  {
    int n4 = NTOK * DM_N / 4;  // 1,048,576
    split_bf16_kernel<<<n4 / 256, 256, 0, stream>>>(x, x_hi, x_lo, n4);
    split_bf16_kernel<<<n4 / 256, 256, 0, stream>>>(in_proj_w, w1_hi, w1_lo, n4);
  }
  // 2) xz = x @ in_proj_w.T : M=4096 N=4096 K=1024, grid 1024
  gemm_bf16x3_nt<<<1024, 256, 0, stream>>>(x_hi, x_lo, w1_hi, w1_lo, xz,
                                           2 * DI_N, DM_N, 32);
  // 3) conv + silu (reads xz, writes u2 over the conversion region)
  {
    int nblk = (int)(((size_t)NTOK * DI_N + 255) / 256);
    conv_silu_kernel<<<nblk, 256, 0, stream>>>(xz, conv_w, conv_b, u2);
  }
  // 4) split out_proj_w (into dead part of xz region)
  {
    int n4 = DM_N * DI_N / 4;  // 524,288
    split_bf16_kernel<<<n4 / 256, 256, 0, stream>>>(out_proj_w, w2_hi, w2_lo, n4);
  }
  // 5) proj = u2 @ x_proj_w.T
  xproj_kernel<<<NTOK / 64, 256, 0, stream>>>(u2, x_proj_w, proj);
  // 6) chunked selective scan -> y (bf16 hi/lo)
  {
    int nblk = B_N * (DI_N / 16) * NC;  // 8192
    scan_pass1_kernel<<<nblk, 256, 0, stream>>>(u2, proj, dt_proj_w, dt_proj_b,
                                                A_log, carryH, carryP);
    scan_fixup_kernel<<<(B_N * DI_N * DS_N) / 256, 256, 0, stream>>>(carryH, carryP);
    scan_pass2_kernel<<<nblk, 256, 0, stream>>>(u2, proj, dt_proj_w, dt_proj_b,
                                                A_log, Dp, carryH, y_hi, y_lo);
  }
  // 7) out = y @ out_proj_w.T : M=4096 N=1024 K=2048, grid 256
  gemm_bf16x3_nt<<<256, 256, 0, stream>>>(y_hi, y_lo, w2_hi, w2_lo, out,
                                          DM_N, DI_N, 8);
}

// Round 4
// 583.255 us; speedup vs baseline: 2.8227x; 1.4501x over previous
//
#include <hip/hip_runtime.h>
#include <hip/hip_bf16.h>
#include <cstddef>
#include <cstdint>

#define B_N 2
#define L_N 2048
#define DM_N 1024
#define DS_N 16
#define DI_N 2048
#define NTOK (B_N * L_N)   // 4096
#define NPROJ 33           // 2*DS+1
#define NC 32              // scan chunks
#define CL (L_N / NC)      // 64 steps per chunk

typedef __attribute__((ext_vector_type(8))) short short8v;
typedef __attribute__((ext_vector_type(4))) float f32x4;
typedef __attribute__((address_space(1))) void av1;
typedef __attribute__((address_space(3))) void av3;

__device__ __forceinline__ void gload16(const void* g, void* l) {
  __builtin_amdgcn_global_load_lds((av1*)g, (av3*)l, 16, 0, 0);
}

__device__ __forceinline__ unsigned short f2bf_rn(float f) {
  uint32_t u = __float_as_uint(f);
  uint32_t r = (u + 0x7fffu + ((u >> 16) & 1u)) >> 16;
  return (unsigned short)r;
}
__device__ __forceinline__ float bf2f(unsigned short h) {
  return __uint_as_float((uint32_t)h << 16);
}

// ---------------------------------------------------------------------------
// Split fp32 -> packed [row][kgroup8][16B hi | 16B lo]. 8 elements/thread.
// ---------------------------------------------------------------------------
__global__ __launch_bounds__(256) void split_pack_kernel(
    const float* __restrict__ src, uint32_t* __restrict__ dst, int n8) {
  int idx = blockIdx.x * 256 + threadIdx.x;
  if (idx >= n8) return;
  const float4* s = (const float4*)src + (size_t)idx * 2;
  float4 v0 = s[0], v1 = s[1];
  float f[8] = {v0.x, v0.y, v0.z, v0.w, v1.x, v1.y, v1.z, v1.w};
  uint32_t hi[4], lo[4];
#pragma unroll
  for (int j = 0; j < 4; ++j) {
    unsigned short h0 = f2bf_rn(f[2 * j]);
    unsigned short h1 = f2bf_rn(f[2 * j + 1]);
    unsigned short l0 = f2bf_rn(f[2 * j] - bf2f(h0));
    unsigned short l1 = f2bf_rn(f[2 * j + 1] - bf2f(h1));
    hi[j] = (uint32_t)h0 | ((uint32_t)h1 << 16);
    lo[j] = (uint32_t)l0 | ((uint32_t)l1 << 16);
  }
  uint4* d = (uint4*)dst + (size_t)idx * 2;
  d[0] = make_uint4(hi[0], hi[1], hi[2], hi[3]);
  d[1] = make_uint4(lo[0], lo[1], lo[2], lo[3]);
}

// ---------------------------------------------------------------------------
// Packed split-bf16 NT GEMM: C[m,n] = sum_k A[m,k]*B[n,k] with A=Ah+Al etc.
// Packed operand layout: [row][g][16B hi|16B lo], 4B/elem, row stride K4=4K.
// 128x128 tile, BK=32, 4 waves (2x2), 3 MFMA per fragment pair.
// LDS: row-major [matrix][r][slot], phys slot = logical ^ (r&7); the XOR is
// baked into the per-lane GLOBAL source address (linear gload_lds dest).
// ---------------------------------------------------------------------------
__global__ __launch_bounds__(256) void gemm_pk_nt(
    const char* __restrict__ Apk, const char* __restrict__ Bpk,
    float* __restrict__ C, int N, int K4, int gx) {
  __shared__ __align__(16) char lds[32768];
  const int tid = threadIdx.x;
  const int lane = tid & 63;
  const int wave = tid >> 6;

  // XCD-aware swizzle (grid divisible by 8)
  const int nwg = gridDim.x;
  const int cpx = nwg >> 3;
  const int bid = blockIdx.x;
  const int wg = (bid & 7) * cpx + (bid >> 3);
  const int bx = wg % gx;
  const int by = wg / gx;
  const int m0 = by * 128, n0 = bx * 128;

  const int wr = wave >> 1, wc = wave & 1;

  // Staging: wave 0: A rows 0-63 | 1: A 64-127 | 2: B 0-63 | 3: B 64-127.
  // Load c covers rows c*8+(lane>>3), slot (lane&7), source slot XOR'd.
  const char* gbase = (wave & 2) ? Bpk : Apk;
  const int rowbase = ((wave & 2) ? n0 : m0) + (wave & 1) * 64;
  const int rloc = lane >> 3;
  const int sslot = (lane & 7) ^ rloc;
  const char* gsrc = gbase + (size_t)(rowbase + rloc) * K4 + sslot * 16;
  const size_t cstride = (size_t)8 * K4;
  char* ldst = lds + wave * 8192 + lane * 16;

  f32x4 acc[4][4] = {};
  const int fr = lane & 15;
  const int fg = lane >> 4;
  const int sA = ((fg * 2) ^ (fr & 7)) * 16;
  const int abase = (wr * 64 + fr) * 128 + sA;
  const int bbase = 16384 + (wc * 64 + fr) * 128 + sA;

  for (int kt4 = 0; kt4 < K4; kt4 += 128) {
#pragma unroll
    for (int c = 0; c < 8; ++c)
      gload16(gsrc + c * cstride + kt4, ldst + c * 1024);
    __syncthreads();

    short8v afh[4], afl[4], bfh[4], bfl[4];
#pragma unroll
    for (int m = 0; m < 4; ++m) {
      int a = abase + m * 2048;
      afh[m] = *(const short8v*)(lds + a);
      afl[m] = *(const short8v*)(lds + (a ^ 16));
    }
#pragma unroll
    for (int n = 0; n < 4; ++n) {
      int b = bbase + n * 2048;
      bfh[n] = *(const short8v*)(lds + b);
      bfl[n] = *(const short8v*)(lds + (b ^ 16));
    }
#pragma unroll
    for (int m = 0; m < 4; ++m) {
#pragma unroll
      for (int n = 0; n < 4; ++n) {
        asm("v_mfma_f32_16x16x32_bf16 %0, %1, %2, %0"
            : "+v"(acc[m][n]) : "v"(afh[m]), "v"(bfh[n]));
        asm("v_mfma_f32_16x16x32_bf16 %0, %1, %2, %0"
            : "+v"(acc[m][n]) : "v"(afh[m]), "v"(bfl[n]));
        asm("v_mfma_f32_16x16x32_bf16 %0, %1, %2, %0"
            : "+v"(acc[m][n]) : "v"(afl[m]), "v"(bfh[n]));
      }
    }
    __syncthreads();
  }

#pragma unroll
  for (int m = 0; m < 4; ++m) {
#pragma unroll
    for (int n = 0; n < 4; ++n) {
#pragma unroll
      for (int q = 0; q < 4; ++q) {
        int row = m0 + wr * 64 + m * 16 + fg * 4 + q;
        int col = n0 + wc * 64 + n * 16 + fr;
        C[(size_t)row * N + col] = acc[m][n][q];
      }
    }
  }
}

// ---------------------------------------------------------------------------
// Depthwise causal conv (DC=4) + bias, times silu(z). Reads xz = [u | z].
// ---------------------------------------------------------------------------
__global__ __launch_bounds__(256) void conv_silu_kernel(
    const float* __restrict__ xz, const float* __restrict__ cw,
    const float* __restrict__ cb, float* __restrict__ u2) {
  size_t idx = (size_t)blockIdx.x * 256 + threadIdx.x;
  if (idx >= (size_t)NTOK * DI_N) return;
  int i = (int)(idx & (DI_N - 1));
  int n = (int)(idx >> 11);
  int l = n & (L_N - 1);
  const float* base = xz + (size_t)n * (2 * DI_N) + i;
  const float4 w = *(const float4*)&cw[i * 4];
  float acc = fmaf(w.w, base[0], cb[i]);
  if (l >= 1) acc = fmaf(w.z, base[-(ptrdiff_t)(2 * DI_N)], acc);
  if (l >= 2) acc = fmaf(w.y, base[-(ptrdiff_t)(4 * DI_N)], acc);
  if (l >= 3) acc = fmaf(w.x, base[-(ptrdiff_t)(6 * DI_N)], acc);
  float z = base[DI_N];
  float sil = z / (1.f + __expf(-z));
  u2[(size_t)n * DI_N + i] = acc * sil;
}

// ---------------------------------------------------------------------------
// proj[n,r] = sum_k u2[n,k] * xw[r,k], r < 33.
// ---------------------------------------------------------------------------
__global__ __launch_bounds__(256) void xproj_kernel(
    const float* __restrict__ u2, const float* __restrict__ xw,
    float* __restrict__ proj) {
  __shared__ float uS[64][129];
  __shared__ float wS[36][128];
  const int tid = threadIdx.x;
  const int row0 = blockIdx.x * 64;
  const int crow = tid & 63;
  const int cg = tid >> 6;
  float acc[9];
#pragma unroll
  for (int j = 0; j < 9; ++j) acc[j] = 0.f;

  for (int kt = 0; kt < DI_N; kt += 128) {
    __syncthreads();
#pragma unroll
    for (int it = 0; it < 8; ++it) {
      int r = (tid >> 5) + it * 8;
      int kq = (tid & 31) << 2;
      float4 v = *(const float4*)&u2[(size_t)(row0 + r) * DI_N + kt + kq];
      uS[r][kq + 0] = v.x; uS[r][kq + 1] = v.y;
      uS[r][kq + 2] = v.z; uS[r][kq + 3] = v.w;
    }
    for (int s = tid; s < 36 * 128; s += 256) {
      int r = s >> 7, k = s & 127;
      wS[r][k] = (r < NPROJ) ? xw[(size_t)r * DI_N + kt + k] : 0.f;
    }
    __syncthreads();
#pragma unroll 4
    for (int k = 0; k < 128; ++k) {
      float uv = uS[crow][k];
#pragma unroll
      for (int j = 0; j < 9; ++j) acc[j] = fmaf(uv, wS[cg * 9 + j][k], acc[j]);
    }
  }
#pragma unroll
  for (int j = 0; j < 9; ++j) {
    int c = cg * 9 + j;
    if (c < NPROJ) proj[(size_t)(row0 + crow) * NPROJ + c] = acc[j];
  }
}

// ---------------------------------------------------------------------------
// Chunked selective scan, pass 1: per (b,i,s,chunk) from h=0, emit H and P.
// ---------------------------------------------------------------------------
__global__ __launch_bounds__(256) void scan_pass1_kernel(
    const float* __restrict__ u2, const float* __restrict__ proj,
    const float* __restrict__ dtw, const float* __restrict__ dtb,
    const float* __restrict__ A_log,
    float* __restrict__ carryH, float* __restrict__ carryP) {
  const int tid = threadIdx.x;
  const int s = tid & 15;
  const int ci = tid >> 4;
  const int bid = blockIdx.x;
  const int c = bid & (NC - 1);
  const int rest = bid >> 5;
  const int ib = rest & 127;
  const int b = rest >> 7;
  const int i = ib * 16 + ci;

  const float A = -__expf(A_log[i * DS_N + s]);
  const float w = dtw[i];
  const float bia = dtb[i];
  float h = 0.f, P = 1.f;

  const int l0 = c * CL;
  const float* un = u2 + ((size_t)b * L_N + l0) * DI_N + i;
  const float* pr = proj + ((size_t)b * L_N + l0) * NPROJ;

#pragma unroll 4
  for (int l = 0; l < CL; ++l) {
    float uv = un[(size_t)l * DI_N];
    float d0 = pr[l * NPROJ];
    float Bt = pr[l * NPROJ + 1 + s];
    float dte = 1.f + __expf(fmaf(d0, w, bia));
    float a = __expf(A * dte);
    h = fmaf(a, h, Bt * dte * uv);
    P *= a;
  }
  size_t cidx = ((size_t)c * B_N + b) * (DI_N * DS_N) + i * DS_N + s;
  carryH[cidx] = h;
  carryP[cidx] = P;
}

// ---------------------------------------------------------------------------
// Fixup: chain chunk carries; carryH[c] <- incoming state for chunk c.
// ---------------------------------------------------------------------------
__global__ __launch_bounds__(256) void scan_fixup_kernel(
    float* __restrict__ carryH, const float* __restrict__ carryP) {
  const int q = blockIdx.x * 256 + threadIdx.x;
  float h = 0.f;
#pragma unroll 4
  for (int c = 0; c < NC; ++c) {
    size_t idx = (size_t)c * (B_N * DI_N * DS_N) + q;
    float Hc = carryH[idx];
    float Pc = carryP[idx];
    carryH[idx] = h;
    h = fmaf(Pc, h, Hc);
  }
}

// ---------------------------------------------------------------------------
// Pass 2: re-run chunks from exact carry; emit y in PACKED hi/lo form.
// ---------------------------------------------------------------------------
__global__ __launch_bounds__(256) void scan_pass2_kernel(
    const float* __restrict__ u2, const float* __restrict__ proj,
    const float* __restrict__ dtw, const float* __restrict__ dtb,
    const float* __restrict__ A_log, const float* __restrict__ Dp,
    const float* __restrict__ carryH, char* __restrict__ ypk) {
  const int tid = threadIdx.x;
  const int s = tid & 15;
  const int ci = tid >> 4;
  const int bid = blockIdx.x;
  const int c = bid & (NC - 1);
  const int rest = bid >> 5;
  const int ib = rest & 127;
  const int b = rest >> 7;
  const int i = ib * 16 + ci;

  const float A = -__expf(A_log[i * DS_N + s]);
  const float w = dtw[i];
  const float bia = dtb[i];
  const float Dd = Dp[i];
  float h = carryH[((size_t)c * B_N + b) * (DI_N * DS_N) + i * DS_N + s];

  const int l0 = c * CL;
  const float* un = u2 + ((size_t)b * L_N + l0) * DI_N + i;
  const float* pr = proj + ((size_t)b * L_N + l0) * NPROJ;
  char* yb = ypk + ((size_t)b * L_N + l0) * (DI_N * 4) + (i >> 3) * 32 + (i & 7) * 2;

#pragma unroll 2
  for (int l = 0; l < CL; ++l) {
    float uv = un[(size_t)l * DI_N];
    float d0 = pr[l * NPROJ];
    float Bt = pr[l * NPROJ + 1 + s];
    float Ct = pr[l * NPROJ + 17 + s];
    float dte = 1.f + __expf(fmaf(d0, w, bia));
    float a = __expf(A * dte);
    h = fmaf(a, h, Bt * dte * uv);
    float p = h * Ct;
    p += __shfl_xor(p, 1, 64);
    p += __shfl_xor(p, 2, 64);
    p += __shfl_xor(p, 4, 64);
    p += __shfl_xor(p, 8, 64);
    if (s == 0) {
      float yv = fmaf(Dd, uv, p);
      unsigned short hh = f2bf_rn(yv);
      char* q = yb + (size_t)l * (DI_N * 4);
      *(unsigned short*)q = hh;
      *(unsigned short*)(q + 16) = f2bf_rn(yv - bf2f(hh));
    }
  }
}

// ---------------------------------------------------------------------------
extern "C" void kernel_launch(void* const* d_in, const int* in_sizes, int n_in,
                              void* d_out, int out_size, void* d_ws, size_t ws_size,
                              hipStream_t stream) {
  const float* x          = (const float*)d_in[0];
  const float* in_proj_w  = (const float*)d_in[1];
  const float* conv_w     = (const float*)d_in[2];
  const float* conv_b     = (const float*)d_in[3];
  const float* x_proj_w   = (const float*)d_in[4];
  const float* dt_proj_w  = (const float*)d_in[5];
  const float* dt_proj_b  = (const float*)d_in[6];
  const float* A_log      = (const float*)d_in[7];
  const float* Dp         = (const float*)d_in[8];
  const float* out_proj_w = (const float*)d_in[9];
  float* out = (float*)d_out;

  char* ws = (char*)d_ws;
  float* xz = (float*)ws;                                        // [0, 67.1MB)
  float* u2 = (float*)(ws + (size_t)NTOK * 2 * DI_N * 4);        // [67.1, 100.7)
  float* proj = (float*)(ws + (size_t)NTOK * 2 * DI_N * 4
                            + (size_t)NTOK * DI_N * 4);          // [100.7, 101.2)

  // packed x / in_proj_w live in the u2 region (dead until conv_silu)
  char* x_pk  = (char*)u2;                                  // 16.78MB
  char* w1_pk = x_pk + (size_t)NTOK * DM_N * 4;             // 16.78MB (fills u2 region)

  // xz region reuse after conv_silu
  char* y_pk = (char*)xz;                                        // 33.55MB
  float* carryH = (float*)(y_pk + (size_t)NTOK * DI_N * 4);      // 8.39MB
  float* carryP = carryH + (size_t)NC * B_N * DI_N * DS_N;       // 8.39MB
  char* w2_pk = (char*)(carryP + (size_t)NC * B_N * DI_N * DS_N);// 8.39MB (ends 58.7MB)

  // 1) split+pack x and in_proj_w
  {
    int n8 = NTOK * DM_N / 8;  // 524288
    split_pack_kernel<<<n8 / 256, 256, 0, stream>>>(x, (uint32_t*)x_pk, n8);
    split_pack_kernel<<<n8 / 256, 256, 0, stream>>>(in_proj_w, (uint32_t*)w1_pk, n8);
  }
  // 2) xz = x @ in_proj_w.T : M=4096 N=4096 K=1024 (K4=4096B), grid 1024
  gemm_pk_nt<<<1024, 256, 0, stream>>>(x_pk, w1_pk, xz, 2 * DI_N, DM_N * 4, 32);
  // 3) conv + silu (reads xz, writes u2 over the packed x/w1 region)
  {
    int nblk = (int)(((size_t)NTOK * DI_N + 255) / 256);
    conv_silu_kernel<<<nblk, 256, 0, stream>>>(xz, conv_w, conv_b, u2);
  }
  // 4) split+pack out_proj_w (into dead part of xz region; xz already consumed)
  {
    int n8 = DM_N * DI_N / 8;  // 262144
    split_pack_kernel<<<n8 / 256, 256, 0, stream>>>(out_proj_w, (uint32_t*)w2_pk, n8);
  }
  // 5) proj = u2 @ x_proj_w.T
  xproj_kernel<<<NTOK / 64, 256, 0, stream>>>(u2, x_proj_w, proj);
  // 6) chunked selective scan -> packed y
  {
    int nblk = B_N * (DI_N / 16) * NC;  // 8192
    scan_pass1_kernel<<<nblk, 256, 0, stream>>>(u2, proj, dt_proj_w, dt_proj_b,
                                                A_log, carryH, carryP);
    scan_fixup_kernel<<<(B_N * DI_N * DS_N) / 256, 256, 0, stream>>>(carryH, carryP);
    scan_pass2_kernel<<<nblk, 256, 0, stream>>>(u2, proj, dt_proj_w, dt_proj_b,
                                                A_log, Dp, carryH, y_pk);
  }
  // 7) out = y @ out_proj_w.T : M=4096 N=1024 K=2048 (K4=8192B), grid 256
  gemm_pk_nt<<<256, 256, 0, stream>>>(y_pk, w2_pk, out, DM_N, DI_N * 4, 8);
}

// Round 5
// 456.714 us; speedup vs baseline: 3.6048x; 1.2771x over previous
//
#include <hip/hip_runtime.h>
#include <hip/hip_bf16.h>
#include <cstddef>
#include <cstdint>

#define B_N 2
#define L_N 2048
#define DM_N 1024
#define DS_N 16
#define DI_N 2048
#define NTOK (B_N * L_N)   // 4096
#define NPROJ 33           // 2*DS+1
#define NC 32              // scan chunks
#define CL (L_N / NC)      // 64 steps per chunk
#define XKC 8              // xproj K-split
#define XKCL (DI_N / XKC)  // 256

typedef __attribute__((ext_vector_type(8))) short short8v;
typedef __attribute__((ext_vector_type(4))) float f32x4;
typedef __attribute__((address_space(1))) void av1;
typedef __attribute__((address_space(3))) void av3;

__device__ __forceinline__ void gload16(const void* g, void* l) {
  __builtin_amdgcn_global_load_lds((av1*)g, (av3*)l, 16, 0, 0);
}

__device__ __forceinline__ unsigned short f2bf_rn(float f) {
  uint32_t u = __float_as_uint(f);
  uint32_t r = (u + 0x7fffu + ((u >> 16) & 1u)) >> 16;
  return (unsigned short)r;
}
__device__ __forceinline__ float bf2f(unsigned short h) {
  return __uint_as_float((uint32_t)h << 16);
}

// ---------------------------------------------------------------------------
// Split fp32 -> packed [row][kgroup8][16B hi | 16B lo]. 8 elements/thread.
// ---------------------------------------------------------------------------
__global__ __launch_bounds__(256) void split_pack_kernel(
    const float* __restrict__ src, uint32_t* __restrict__ dst, int n8) {
  int idx = blockIdx.x * 256 + threadIdx.x;
  if (idx >= n8) return;
  const float4* s = (const float4*)src + (size_t)idx * 2;
  float4 v0 = s[0], v1 = s[1];
  float f[8] = {v0.x, v0.y, v0.z, v0.w, v1.x, v1.y, v1.z, v1.w};
  uint32_t hi[4], lo[4];
#pragma unroll
  for (int j = 0; j < 4; ++j) {
    unsigned short h0 = f2bf_rn(f[2 * j]);
    unsigned short h1 = f2bf_rn(f[2 * j + 1]);
    unsigned short l0 = f2bf_rn(f[2 * j] - bf2f(h0));
    unsigned short l1 = f2bf_rn(f[2 * j + 1] - bf2f(h1));
    hi[j] = (uint32_t)h0 | ((uint32_t)h1 << 16);
    lo[j] = (uint32_t)l0 | ((uint32_t)l1 << 16);
  }
  uint4* d = (uint4*)dst + (size_t)idx * 2;
  d[0] = make_uint4(hi[0], hi[1], hi[2], hi[3]);
  d[1] = make_uint4(lo[0], lo[1], lo[2], lo[3]);
}

// ---------------------------------------------------------------------------
// Packed split-bf16 NT GEMM (unchanged from round 4).
// ---------------------------------------------------------------------------
__global__ __launch_bounds__(256) void gemm_pk_nt(
    const char* __restrict__ Apk, const char* __restrict__ Bpk,
    float* __restrict__ C, int N, int K4, int gx) {
  __shared__ __align__(16) char lds[32768];
  const int tid = threadIdx.x;
  const int lane = tid & 63;
  const int wave = tid >> 6;

  const int nwg = gridDim.x;
  const int cpx = nwg >> 3;
  const int bid = blockIdx.x;
  const int wg = (bid & 7) * cpx + (bid >> 3);
  const int bx = wg % gx;
  const int by = wg / gx;
  const int m0 = by * 128, n0 = bx * 128;

  const int wr = wave >> 1, wc = wave & 1;

  const char* gbase = (wave & 2) ? Bpk : Apk;
  const int rowbase = ((wave & 2) ? n0 : m0) + (wave & 1) * 64;
  const int rloc = lane >> 3;
  const int sslot = (lane & 7) ^ rloc;
  const char* gsrc = gbase + (size_t)(rowbase + rloc) * K4 + sslot * 16;
  const size_t cstride = (size_t)8 * K4;
  char* ldst = lds + wave * 8192 + lane * 16;

  f32x4 acc[4][4] = {};
  const int fr = lane & 15;
  const int fg = lane >> 4;
  const int sA = ((fg * 2) ^ (fr & 7)) * 16;
  const int abase = (wr * 64 + fr) * 128 + sA;
  const int bbase = 16384 + (wc * 64 + fr) * 128 + sA;

  for (int kt4 = 0; kt4 < K4; kt4 += 128) {
#pragma unroll
    for (int c = 0; c < 8; ++c)
      gload16(gsrc + c * cstride + kt4, ldst + c * 1024);
    __syncthreads();

    short8v afh[4], afl[4], bfh[4], bfl[4];
#pragma unroll
    for (int m = 0; m < 4; ++m) {
      int a = abase + m * 2048;
      afh[m] = *(const short8v*)(lds + a);
      afl[m] = *(const short8v*)(lds + (a ^ 16));
    }
#pragma unroll
    for (int n = 0; n < 4; ++n) {
      int b = bbase + n * 2048;
      bfh[n] = *(const short8v*)(lds + b);
      bfl[n] = *(const short8v*)(lds + (b ^ 16));
    }
#pragma unroll
    for (int m = 0; m < 4; ++m) {
#pragma unroll
      for (int n = 0; n < 4; ++n) {
        asm("v_mfma_f32_16x16x32_bf16 %0, %1, %2, %0"
            : "+v"(acc[m][n]) : "v"(afh[m]), "v"(bfh[n]));
        asm("v_mfma_f32_16x16x32_bf16 %0, %1, %2, %0"
            : "+v"(acc[m][n]) : "v"(afh[m]), "v"(bfl[n]));
        asm("v_mfma_f32_16x16x32_bf16 %0, %1, %2, %0"
            : "+v"(acc[m][n]) : "v"(afl[m]), "v"(bfh[n]));
      }
    }
    __syncthreads();
  }

#pragma unroll
  for (int m = 0; m < 4; ++m) {
#pragma unroll
    for (int n = 0; n < 4; ++n) {
#pragma unroll
      for (int q = 0; q < 4; ++q) {
        int row = m0 + wr * 64 + m * 16 + fg * 4 + q;
        int col = n0 + wc * 64 + n * 16 + fr;
        C[(size_t)row * N + col] = acc[m][n][q];
      }
    }
  }
}

// ---------------------------------------------------------------------------
// Depthwise causal conv (DC=4) + bias, times silu(z). Reads xz = [u | z].
// ---------------------------------------------------------------------------
__global__ __launch_bounds__(256) void conv_silu_kernel(
    const float* __restrict__ xz, const float* __restrict__ cw,
    const float* __restrict__ cb, float* __restrict__ u2) {
  size_t idx = (size_t)blockIdx.x * 256 + threadIdx.x;
  if (idx >= (size_t)NTOK * DI_N) return;
  int i = (int)(idx & (DI_N - 1));
  int n = (int)(idx >> 11);
  int l = n & (L_N - 1);
  const float* base = xz + (size_t)n * (2 * DI_N) + i;
  const float4 w = *(const float4*)&cw[i * 4];
  float acc = fmaf(w.w, base[0], cb[i]);
  if (l >= 1) acc = fmaf(w.z, base[-(ptrdiff_t)(2 * DI_N)], acc);
  if (l >= 2) acc = fmaf(w.y, base[-(ptrdiff_t)(4 * DI_N)], acc);
  if (l >= 3) acc = fmaf(w.x, base[-(ptrdiff_t)(6 * DI_N)], acc);
  float z = base[DI_N];
  float sil = z / (1.f + __expf(-z));
  u2[(size_t)n * DI_N + i] = acc * sil;
}

// ---------------------------------------------------------------------------
// xproj stage 1: partial[kc][n][c] = sum_{k in chunk kc} u2[n,k]*xw[c,k].
// Block: 16 rows x 256-k chunk. Thread: (row r = t&15, col group cg = t>>4,
// 3 cols each, cols >= 33 masked). LDS stride 257 floats (bank-free).
// ---------------------------------------------------------------------------
__global__ __launch_bounds__(256) void xproj_part_kernel(
    const float* __restrict__ u2, const float* __restrict__ xw,
    float* __restrict__ part) {
  __shared__ float uS[16][257];
  __shared__ float wS[33][257];
  const int tid = threadIdx.x;
  const int kc = blockIdx.x & (XKC - 1);
  const int rb = blockIdx.x >> 3;
  const int row0 = rb * 16;
  const int k0 = kc * XKCL;

#pragma unroll
  for (int it = 0; it < 4; ++it) {
    int slot = tid + it * 256;          // 0..1023
    int r = slot >> 6;
    int kq = (slot & 63) << 2;
    float4 v = *(const float4*)&u2[(size_t)(row0 + r) * DI_N + k0 + kq];
    uS[r][kq] = v.x; uS[r][kq + 1] = v.y;
    uS[r][kq + 2] = v.z; uS[r][kq + 3] = v.w;
  }
#pragma unroll
  for (int it = 0; it < 9; ++it) {
    int slot = tid + it * 256;
    if (slot < 33 * 64) {
      int c = slot >> 6;
      int kq = (slot & 63) << 2;
      float4 v = *(const float4*)&xw[(size_t)c * DI_N + k0 + kq];
      wS[c][kq] = v.x; wS[c][kq + 1] = v.y;
      wS[c][kq + 2] = v.z; wS[c][kq + 3] = v.w;
    }
  }
  __syncthreads();

  const int r = tid & 15;
  const int cg = tid >> 4;
  const int c0 = cg * 3;
  const int rc0 = c0 > 32 ? 32 : c0;
  const int rc1 = c0 + 1 > 32 ? 32 : c0 + 1;
  const int rc2 = c0 + 2 > 32 ? 32 : c0 + 2;
  float a0 = 0.f, a1 = 0.f, a2 = 0.f;
#pragma unroll 4
  for (int k = 0; k < XKCL; ++k) {
    float uv = uS[r][k];
    a0 = fmaf(uv, wS[rc0][k], a0);
    a1 = fmaf(uv, wS[rc1][k], a1);
    a2 = fmaf(uv, wS[rc2][k], a2);
  }
  size_t base = (size_t)kc * (NTOK * NPROJ) + (size_t)(row0 + r) * NPROJ;
  if (c0 < NPROJ)     part[base + c0] = a0;
  if (c0 + 1 < NPROJ) part[base + c0 + 1] = a1;
  if (c0 + 2 < NPROJ) part[base + c0 + 2] = a2;
}

// ---------------------------------------------------------------------------
// xproj stage 2: proj = sum over the 8 K-chunk partials (fixed order).
// ---------------------------------------------------------------------------
__global__ __launch_bounds__(256) void xproj_reduce_kernel(
    const float* __restrict__ part, float* __restrict__ proj) {
  int idx = blockIdx.x * 256 + threadIdx.x;  // < NTOK*NPROJ = 135168
  float s = 0.f;
#pragma unroll
  for (int kc = 0; kc < XKC; ++kc)
    s += part[(size_t)kc * (NTOK * NPROJ) + idx];
  proj[idx] = s;
}

// ---------------------------------------------------------------------------
// Chunked selective scan, pass 1: per (b,i,s,chunk) from h=0, emit H and P.
// ---------------------------------------------------------------------------
__global__ __launch_bounds__(256) void scan_pass1_kernel(
    const float* __restrict__ u2, const float* __restrict__ proj,
    const float* __restrict__ dtw, const float* __restrict__ dtb,
    const float* __restrict__ A_log,
    float* __restrict__ carryH, float* __restrict__ carryP) {
  const int tid = threadIdx.x;
  const int s = tid & 15;
  const int ci = tid >> 4;
  const int bid = blockIdx.x;
  const int c = bid & (NC - 1);
  const int rest = bid >> 5;
  const int ib = rest & 127;
  const int b = rest >> 7;
  const int i = ib * 16 + ci;

  const float A = -__expf(A_log[i * DS_N + s]);
  const float w = dtw[i];
  const float bia = dtb[i];
  float h = 0.f, P = 1.f;

  const int l0 = c * CL;
  const float* un = u2 + ((size_t)b * L_N + l0) * DI_N + i;
  const float* pr = proj + ((size_t)b * L_N + l0) * NPROJ;

#pragma unroll 4
  for (int l = 0; l < CL; ++l) {
    float uv = un[(size_t)l * DI_N];
    float d0 = pr[l * NPROJ];
    float Bt = pr[l * NPROJ + 1 + s];
    float dte = 1.f + __expf(fmaf(d0, w, bia));
    float a = __expf(A * dte);
    h = fmaf(a, h, Bt * dte * uv);
    P *= a;
  }
  size_t cidx = ((size_t)c * B_N + b) * (DI_N * DS_N) + i * DS_N + s;
  carryH[cidx] = h;
  carryP[cidx] = P;
}

// ---------------------------------------------------------------------------
// Fixup: chain chunk carries; carryH[c] <- incoming state for chunk c.
// ---------------------------------------------------------------------------
__global__ __launch_bounds__(256) void scan_fixup_kernel(
    float* __restrict__ carryH, const float* __restrict__ carryP) {
  const int q = blockIdx.x * 256 + threadIdx.x;
  float h = 0.f;
#pragma unroll 4
  for (int c = 0; c < NC; ++c) {
    size_t idx = (size_t)c * (B_N * DI_N * DS_N) + q;
    float Hc = carryH[idx];
    float Pc = carryP[idx];
    carryH[idx] = h;
    h = fmaf(Pc, h, Hc);
  }
}

// ---------------------------------------------------------------------------
// Pass 2: re-run chunks from exact carry; emit y in PACKED hi/lo form.
// ---------------------------------------------------------------------------
__global__ __launch_bounds__(256) void scan_pass2_kernel(
    const float* __restrict__ u2, const float* __restrict__ proj,
    const float* __restrict__ dtw, const float* __restrict__ dtb,
    const float* __restrict__ A_log, const float* __restrict__ Dp,
    const float* __restrict__ carryH, char* __restrict__ ypk) {
  const int tid = threadIdx.x;
  const int s = tid & 15;
  const int ci = tid >> 4;
  const int bid = blockIdx.x;
  const int c = bid & (NC - 1);
  const int rest = bid >> 5;
  const int ib = rest & 127;
  const int b = rest >> 7;
  const int i = ib * 16 + ci;

  const float A = -__expf(A_log[i * DS_N + s]);
  const float w = dtw[i];
  const float bia = dtb[i];
  const float Dd = Dp[i];
  float h = carryH[((size_t)c * B_N + b) * (DI_N * DS_N) + i * DS_N + s];

  const int l0 = c * CL;
  const float* un = u2 + ((size_t)b * L_N + l0) * DI_N + i;
  const float* pr = proj + ((size_t)b * L_N + l0) * NPROJ;
  char* yb = ypk + ((size_t)b * L_N + l0) * (DI_N * 4) + (i >> 3) * 32 + (i & 7) * 2;

#pragma unroll 2
  for (int l = 0; l < CL; ++l) {
    float uv = un[(size_t)l * DI_N];
    float d0 = pr[l * NPROJ];
    float Bt = pr[l * NPROJ + 1 + s];
    float Ct = pr[l * NPROJ + 17 + s];
    float dte = 1.f + __expf(fmaf(d0, w, bia));
    float a = __expf(A * dte);
    h = fmaf(a, h, Bt * dte * uv);
    float p = h * Ct;
    p += __shfl_xor(p, 1, 64);
    p += __shfl_xor(p, 2, 64);
    p += __shfl_xor(p, 4, 64);
    p += __shfl_xor(p, 8, 64);
    if (s == 0) {
      float yv = fmaf(Dd, uv, p);
      unsigned short hh = f2bf_rn(yv);
      char* q = yb + (size_t)l * (DI_N * 4);
      *(unsigned short*)q = hh;
      *(unsigned short*)(q + 16) = f2bf_rn(yv - bf2f(hh));
    }
  }
}

// ---------------------------------------------------------------------------
extern "C" void kernel_launch(void* const* d_in, const int* in_sizes, int n_in,
                              void* d_out, int out_size, void* d_ws, size_t ws_size,
                              hipStream_t stream) {
  const float* x          = (const float*)d_in[0];
  const float* in_proj_w  = (const float*)d_in[1];
  const float* conv_w     = (const float*)d_in[2];
  const float* conv_b     = (const float*)d_in[3];
  const float* x_proj_w   = (const float*)d_in[4];
  const float* dt_proj_w  = (const float*)d_in[5];
  const float* dt_proj_b  = (const float*)d_in[6];
  const float* A_log      = (const float*)d_in[7];
  const float* Dp         = (const float*)d_in[8];
  const float* out_proj_w = (const float*)d_in[9];
  float* out = (float*)d_out;

  char* ws = (char*)d_ws;
  float* xz = (float*)ws;                                        // [0, 67.1MB)
  float* u2 = (float*)(ws + (size_t)NTOK * 2 * DI_N * 4);        // [67.1, 100.7)
  float* proj = (float*)(ws + (size_t)NTOK * 2 * DI_N * 4
                            + (size_t)NTOK * DI_N * 4);          // [100.7, 101.2)

  // packed x / in_proj_w live in the u2 region (dead until conv_silu)
  char* x_pk  = (char*)u2;                                  // 16.78MB
  char* w1_pk = x_pk + (size_t)NTOK * DM_N * 4;             // 16.78MB

  // xz region reuse after conv_silu
  char* y_pk = (char*)xz;                                        // 33.55MB
  float* carryH = (float*)(y_pk + (size_t)NTOK * DI_N * 4);      // 8.39MB
  float* carryP = carryH + (size_t)NC * B_N * DI_N * DS_N;       // 8.39MB
  char* w2_pk = (char*)(carryP + (size_t)NC * B_N * DI_N * DS_N);// 8.39MB (ends 58.7MB)
  float* xpart = (float*)(w2_pk + (size_t)DM_N * DI_N * 4);      // 4.33MB (ends 63.1MB)

  // 1) split+pack x and in_proj_w
  {
    int n8 = NTOK * DM_N / 8;  // 524288
    split_pack_kernel<<<n8 / 256, 256, 0, stream>>>(x, (uint32_t*)x_pk, n8);
    split_pack_kernel<<<n8 / 256, 256, 0, stream>>>(in_proj_w, (uint32_t*)w1_pk, n8);
  }
  // 2) xz = x @ in_proj_w.T : M=4096 N=4096 K=1024 (K4=4096B), grid 1024
  gemm_pk_nt<<<1024, 256, 0, stream>>>(x_pk, w1_pk, xz, 2 * DI_N, DM_N * 4, 32);
  // 3) conv + silu
  {
    int nblk = (int)(((size_t)NTOK * DI_N + 255) / 256);
    conv_silu_kernel<<<nblk, 256, 0, stream>>>(xz, conv_w, conv_b, u2);
  }
  // 4) split+pack out_proj_w
  {
    int n8 = DM_N * DI_N / 8;  // 262144
    split_pack_kernel<<<n8 / 256, 256, 0, stream>>>(out_proj_w, (uint32_t*)w2_pk, n8);
  }
  // 5) proj = u2 @ x_proj_w.T  (2-stage K-split)
  {
    xproj_part_kernel<<<(NTOK / 16) * XKC, 256, 0, stream>>>(u2, x_proj_w, xpart);
    xproj_reduce_kernel<<<(NTOK * NPROJ) / 256, 256, 0, stream>>>(xpart, proj);
  }
  // 6) chunked selective scan -> packed y
  {
    int nblk = B_N * (DI_N / 16) * NC;  // 8192
    scan_pass1_kernel<<<nblk, 256, 0, stream>>>(u2, proj, dt_proj_w, dt_proj_b,
                                                A_log, carryH, carryP);
    scan_fixup_kernel<<<(B_N * DI_N * DS_N) / 256, 256, 0, stream>>>(carryH, carryP);
    scan_pass2_kernel<<<nblk, 256, 0, stream>>>(u2, proj, dt_proj_w, dt_proj_b,
                                                A_log, Dp, carryH, y_pk);
  }
  // 7) out = y @ out_proj_w.T : M=4096 N=1024 K=2048 (K4=8192B), grid 256
  gemm_pk_nt<<<256, 256, 0, stream>>>(y_pk, w2_pk, out, DM_N, DI_N * 4, 8);
}

// Round 6
// 434.182 us; speedup vs baseline: 3.7919x; 1.0519x over previous
//
#include <hip/hip_runtime.h>
#include <hip/hip_bf16.h>
#include <cstddef>
#include <cstdint>

#define B_N 2
#define L_N 2048
#define DM_N 1024
#define DS_N 16
#define DI_N 2048
#define NTOK (B_N * L_N)   // 4096
#define NPROJ 33           // 2*DS+1
#define NPJ 36             // padded proj row: d0@0, B@4..19, C@20..35
#define NC 32              // scan chunks
#define CL (L_N / NC)      // 64 steps per chunk
#define XKC 8              // xproj K-split
#define XKCL (DI_N / XKC)  // 256

typedef __attribute__((ext_vector_type(8))) short short8v;
typedef __attribute__((ext_vector_type(4))) float f32x4;
typedef __attribute__((address_space(1))) void av1;
typedef __attribute__((address_space(3))) void av3;

__device__ __forceinline__ void gload16(const void* g, void* l) {
  __builtin_amdgcn_global_load_lds((av1*)g, (av3*)l, 16, 0, 0);
}

__device__ __forceinline__ unsigned short f2bf_rn(float f) {
  uint32_t u = __float_as_uint(f);
  uint32_t r = (u + 0x7fffu + ((u >> 16) & 1u)) >> 16;
  return (unsigned short)r;
}
__device__ __forceinline__ float bf2f(unsigned short h) {
  return __uint_as_float((uint32_t)h << 16);
}

// ---------------------------------------------------------------------------
// Split fp32 -> packed [row][kgroup8][16B hi | 16B lo]. 8 elements/thread.
// ---------------------------------------------------------------------------
__global__ __launch_bounds__(256) void split_pack_kernel(
    const float* __restrict__ src, uint32_t* __restrict__ dst, int n8) {
  int idx = blockIdx.x * 256 + threadIdx.x;
  if (idx >= n8) return;
  const float4* s = (const float4*)src + (size_t)idx * 2;
  float4 v0 = s[0], v1 = s[1];
  float f[8] = {v0.x, v0.y, v0.z, v0.w, v1.x, v1.y, v1.z, v1.w};
  uint32_t hi[4], lo[4];
#pragma unroll
  for (int j = 0; j < 4; ++j) {
    unsigned short h0 = f2bf_rn(f[2 * j]);
    unsigned short h1 = f2bf_rn(f[2 * j + 1]);
    unsigned short l0 = f2bf_rn(f[2 * j] - bf2f(h0));
    unsigned short l1 = f2bf_rn(f[2 * j + 1] - bf2f(h1));
    hi[j] = (uint32_t)h0 | ((uint32_t)h1 << 16);
    lo[j] = (uint32_t)l0 | ((uint32_t)l1 << 16);
  }
  uint4* d = (uint4*)dst + (size_t)idx * 2;
  d[0] = make_uint4(hi[0], hi[1], hi[2], hi[3]);
  d[1] = make_uint4(lo[0], lo[1], lo[2], lo[3]);
}

// ---------------------------------------------------------------------------
// Packed split-bf16 NT GEMM (unchanged).
// ---------------------------------------------------------------------------
__global__ __launch_bounds__(256) void gemm_pk_nt(
    const char* __restrict__ Apk, const char* __restrict__ Bpk,
    float* __restrict__ C, int N, int K4, int gx) {
  __shared__ __align__(16) char lds[32768];
  const int tid = threadIdx.x;
  const int lane = tid & 63;
  const int wave = tid >> 6;

  const int nwg = gridDim.x;
  const int cpx = nwg >> 3;
  const int bid = blockIdx.x;
  const int wg = (bid & 7) * cpx + (bid >> 3);
  const int bx = wg % gx;
  const int by = wg / gx;
  const int m0 = by * 128, n0 = bx * 128;

  const int wr = wave >> 1, wc = wave & 1;

  const char* gbase = (wave & 2) ? Bpk : Apk;
  const int rowbase = ((wave & 2) ? n0 : m0) + (wave & 1) * 64;
  const int rloc = lane >> 3;
  const int sslot = (lane & 7) ^ rloc;
  const char* gsrc = gbase + (size_t)(rowbase + rloc) * K4 + sslot * 16;
  const size_t cstride = (size_t)8 * K4;
  char* ldst = lds + wave * 8192 + lane * 16;

  f32x4 acc[4][4] = {};
  const int fr = lane & 15;
  const int fg = lane >> 4;
  const int sA = ((fg * 2) ^ (fr & 7)) * 16;
  const int abase = (wr * 64 + fr) * 128 + sA;
  const int bbase = 16384 + (wc * 64 + fr) * 128 + sA;

  for (int kt4 = 0; kt4 < K4; kt4 += 128) {
#pragma unroll
    for (int c = 0; c < 8; ++c)
      gload16(gsrc + c * cstride + kt4, ldst + c * 1024);
    __syncthreads();

    short8v afh[4], afl[4], bfh[4], bfl[4];
#pragma unroll
    for (int m = 0; m < 4; ++m) {
      int a = abase + m * 2048;
      afh[m] = *(const short8v*)(lds + a);
      afl[m] = *(const short8v*)(lds + (a ^ 16));
    }
#pragma unroll
    for (int n = 0; n < 4; ++n) {
      int b = bbase + n * 2048;
      bfh[n] = *(const short8v*)(lds + b);
      bfl[n] = *(const short8v*)(lds + (b ^ 16));
    }
#pragma unroll
    for (int m = 0; m < 4; ++m) {
#pragma unroll
      for (int n = 0; n < 4; ++n) {
        asm("v_mfma_f32_16x16x32_bf16 %0, %1, %2, %0"
            : "+v"(acc[m][n]) : "v"(afh[m]), "v"(bfh[n]));
        asm("v_mfma_f32_16x16x32_bf16 %0, %1, %2, %0"
            : "+v"(acc[m][n]) : "v"(afh[m]), "v"(bfl[n]));
        asm("v_mfma_f32_16x16x32_bf16 %0, %1, %2, %0"
            : "+v"(acc[m][n]) : "v"(afl[m]), "v"(bfh[n]));
      }
    }
    __syncthreads();
  }

#pragma unroll
  for (int m = 0; m < 4; ++m) {
#pragma unroll
    for (int n = 0; n < 4; ++n) {
#pragma unroll
      for (int q = 0; q < 4; ++q) {
        int row = m0 + wr * 64 + m * 16 + fg * 4 + q;
        int col = n0 + wc * 64 + n * 16 + fr;
        C[(size_t)row * N + col] = acc[m][n][q];
      }
    }
  }
}

// ---------------------------------------------------------------------------
// Depthwise causal conv (DC=4) + bias, times silu(z). Reads xz = [u | z].
// ---------------------------------------------------------------------------
__global__ __launch_bounds__(256) void conv_silu_kernel(
    const float* __restrict__ xz, const float* __restrict__ cw,
    const float* __restrict__ cb, float* __restrict__ u2) {
  size_t idx = (size_t)blockIdx.x * 256 + threadIdx.x;
  if (idx >= (size_t)NTOK * DI_N) return;
  int i = (int)(idx & (DI_N - 1));
  int n = (int)(idx >> 11);
  int l = n & (L_N - 1);
  const float* base = xz + (size_t)n * (2 * DI_N) + i;
  const float4 w = *(const float4*)&cw[i * 4];
  float acc = fmaf(w.w, base[0], cb[i]);
  if (l >= 1) acc = fmaf(w.z, base[-(ptrdiff_t)(2 * DI_N)], acc);
  if (l >= 2) acc = fmaf(w.y, base[-(ptrdiff_t)(4 * DI_N)], acc);
  if (l >= 3) acc = fmaf(w.x, base[-(ptrdiff_t)(6 * DI_N)], acc);
  float z = base[DI_N];
  float sil = z / (1.f + __expf(-z));
  u2[(size_t)n * DI_N + i] = acc * sil;
}

// ---------------------------------------------------------------------------
// xproj stage 1: partials into padded 36-wide rows: col 0 -> slot 0,
// cols 1..32 -> slots 4..35 (B at 4..19, C at 20..35, all 16B aligned).
// ---------------------------------------------------------------------------
__global__ __launch_bounds__(256) void xproj_part_kernel(
    const float* __restrict__ u2, const float* __restrict__ xw,
    float* __restrict__ part) {
  __shared__ float uS[16][257];
  __shared__ float wS[33][257];
  const int tid = threadIdx.x;
  const int kc = blockIdx.x & (XKC - 1);
  const int rb = blockIdx.x >> 3;
  const int row0 = rb * 16;
  const int k0 = kc * XKCL;

#pragma unroll
  for (int it = 0; it < 4; ++it) {
    int slot = tid + it * 256;
    int r = slot >> 6;
    int kq = (slot & 63) << 2;
    float4 v = *(const float4*)&u2[(size_t)(row0 + r) * DI_N + k0 + kq];
    uS[r][kq] = v.x; uS[r][kq + 1] = v.y;
    uS[r][kq + 2] = v.z; uS[r][kq + 3] = v.w;
  }
#pragma unroll
  for (int it = 0; it < 9; ++it) {
    int slot = tid + it * 256;
    if (slot < 33 * 64) {
      int c = slot >> 6;
      int kq = (slot & 63) << 2;
      float4 v = *(const float4*)&xw[(size_t)c * DI_N + k0 + kq];
      wS[c][kq] = v.x; wS[c][kq + 1] = v.y;
      wS[c][kq + 2] = v.z; wS[c][kq + 3] = v.w;
    }
  }
  __syncthreads();

  const int r = tid & 15;
  const int cg = tid >> 4;
  const int c0 = cg * 3;
  const int rc0 = c0 > 32 ? 32 : c0;
  const int rc1 = c0 + 1 > 32 ? 32 : c0 + 1;
  const int rc2 = c0 + 2 > 32 ? 32 : c0 + 2;
  float a0 = 0.f, a1 = 0.f, a2 = 0.f;
#pragma unroll 4
  for (int k = 0; k < XKCL; ++k) {
    float uv = uS[r][k];
    a0 = fmaf(uv, wS[rc0][k], a0);
    a1 = fmaf(uv, wS[rc1][k], a1);
    a2 = fmaf(uv, wS[rc2][k], a2);
  }
  size_t base = (size_t)kc * (NTOK * NPJ) + (size_t)(row0 + r) * NPJ;
  if (c0 < NPROJ)     part[base + (c0 == 0 ? 0 : c0 + 3)] = a0;
  if (c0 + 1 < NPROJ) part[base + c0 + 4] = a1;
  if (c0 + 2 < NPROJ) part[base + c0 + 5] = a2;
}

// ---------------------------------------------------------------------------
// xproj stage 2: proj36 = sum over the 8 K-chunk partials (fixed order).
// ---------------------------------------------------------------------------
__global__ __launch_bounds__(256) void xproj_reduce_kernel(
    const float* __restrict__ part, float* __restrict__ proj) {
  int idx = blockIdx.x * 256 + threadIdx.x;  // < NTOK*NPJ = 147456
  float s = 0.f;
#pragma unroll
  for (int kc = 0; kc < XKC; ++kc)
    s += part[(size_t)kc * (NTOK * NPJ) + idx];
  proj[idx] = s;
}

// ---------------------------------------------------------------------------
// Scan pass 1: thread = (b, i, chunk); all 16 states in registers.
// a[s] = 2^(A2[s]*dte); chunk product P[s] = 2^(A2[s]*sum dte).
// ---------------------------------------------------------------------------
__global__ __launch_bounds__(256) void scan_pass1_kernel(
    const float* __restrict__ u2, const float* __restrict__ pj,
    const float* __restrict__ dtw, const float* __restrict__ dtb,
    const float* __restrict__ A_log,
    float* __restrict__ carryH, float* __restrict__ carryP) {
  const int t = blockIdx.x * 256 + threadIdx.x;
  const int i = t & (DI_N - 1);
  const int rest = t >> 11;
  const int c = rest & (NC - 1);
  const int b = rest >> 5;
  const float LOG2E = 1.4426950408889634f;

  float A2[16];
#pragma unroll
  for (int q = 0; q < 4; ++q) {
    float4 v = *(const float4*)&A_log[i * DS_N + q * 4];
    A2[q * 4 + 0] = -__expf(v.x) * LOG2E;
    A2[q * 4 + 1] = -__expf(v.y) * LOG2E;
    A2[q * 4 + 2] = -__expf(v.z) * LOG2E;
    A2[q * 4 + 3] = -__expf(v.w) * LOG2E;
  }
  const float wl = dtw[i] * LOG2E;
  const float bl = dtb[i] * LOG2E;

  float h[16] = {};
  float sdte = 0.f;
  const int l0 = c * CL;
  const float* un = u2 + ((size_t)b * L_N + l0) * DI_N + i;
  const float* pr = pj + ((size_t)b * L_N + l0) * NPJ;

#pragma unroll 2
  for (int l = 0; l < CL; ++l) {
    float uv = un[(size_t)l * DI_N];
    const float* row = pr + l * NPJ;
    float d0 = row[0];
    float4 B0 = *(const float4*)(row + 4);
    float4 B1 = *(const float4*)(row + 8);
    float4 B2 = *(const float4*)(row + 12);
    float4 B3 = *(const float4*)(row + 16);
    float dte = 1.f + exp2f(fmaf(d0, wl, bl));
    float du = dte * uv;
    sdte += dte;
    float Bv[16] = {B0.x, B0.y, B0.z, B0.w, B1.x, B1.y, B1.z, B1.w,
                    B2.x, B2.y, B2.z, B2.w, B3.x, B3.y, B3.z, B3.w};
#pragma unroll
    for (int s = 0; s < 16; ++s) {
      float a = exp2f(A2[s] * dte);
      h[s] = fmaf(a, h[s], Bv[s] * du);
    }
  }
  size_t cbase = (((size_t)c * B_N + b) * DI_N + i) * DS_N;
#pragma unroll
  for (int q = 0; q < 4; ++q) {
    float4 hv = {h[q * 4], h[q * 4 + 1], h[q * 4 + 2], h[q * 4 + 3]};
    *(float4*)&carryH[cbase + q * 4] = hv;
    float4 pv = {exp2f(A2[q * 4] * sdte), exp2f(A2[q * 4 + 1] * sdte),
                 exp2f(A2[q * 4 + 2] * sdte), exp2f(A2[q * 4 + 3] * sdte)};
    *(float4*)&carryP[cbase + q * 4] = pv;
  }
}

// ---------------------------------------------------------------------------
// Fixup: chain chunk carries; carryH[c] <- incoming state for chunk c.
// ---------------------------------------------------------------------------
__global__ __launch_bounds__(256) void scan_fixup_kernel(
    float* __restrict__ carryH, const float* __restrict__ carryP) {
  const int q = blockIdx.x * 256 + threadIdx.x;
  float h = 0.f;
#pragma unroll 4
  for (int c = 0; c < NC; ++c) {
    size_t idx = (size_t)c * (B_N * DI_N * DS_N) + q;
    float Hc = carryH[idx];
    float Pc = carryP[idx];
    carryH[idx] = h;
    h = fmaf(Pc, h, Hc);
  }
}

// ---------------------------------------------------------------------------
// Scan pass 2: thread = (b, i, chunk); y in-register; emit packed hi/lo y.
// ---------------------------------------------------------------------------
__global__ __launch_bounds__(256) void scan_pass2_kernel(
    const float* __restrict__ u2, const float* __restrict__ pj,
    const float* __restrict__ dtw, const float* __restrict__ dtb,
    const float* __restrict__ A_log, const float* __restrict__ Dp,
    const float* __restrict__ carryH, char* __restrict__ ypk) {
  const int t = blockIdx.x * 256 + threadIdx.x;
  const int i = t & (DI_N - 1);
  const int rest = t >> 11;
  const int c = rest & (NC - 1);
  const int b = rest >> 5;
  const float LOG2E = 1.4426950408889634f;

  float A2[16];
#pragma unroll
  for (int q = 0; q < 4; ++q) {
    float4 v = *(const float4*)&A_log[i * DS_N + q * 4];
    A2[q * 4 + 0] = -__expf(v.x) * LOG2E;
    A2[q * 4 + 1] = -__expf(v.y) * LOG2E;
    A2[q * 4 + 2] = -__expf(v.z) * LOG2E;
    A2[q * 4 + 3] = -__expf(v.w) * LOG2E;
  }
  const float wl = dtw[i] * LOG2E;
  const float bl = dtb[i] * LOG2E;
  const float Dd = Dp[i];

  float h[16];
  size_t cbase = (((size_t)c * B_N + b) * DI_N + i) * DS_N;
#pragma unroll
  for (int q = 0; q < 4; ++q) {
    float4 hv = *(const float4*)&carryH[cbase + q * 4];
    h[q * 4] = hv.x; h[q * 4 + 1] = hv.y;
    h[q * 4 + 2] = hv.z; h[q * 4 + 3] = hv.w;
  }

  const int l0 = c * CL;
  const float* un = u2 + ((size_t)b * L_N + l0) * DI_N + i;
  const float* pr = pj + ((size_t)b * L_N + l0) * NPJ;
  char* yb = ypk + ((size_t)b * L_N + l0) * (DI_N * 4) + (i >> 3) * 32 + (i & 7) * 2;

#pragma unroll 2
  for (int l = 0; l < CL; ++l) {
    float uv = un[(size_t)l * DI_N];
    const float* row = pr + l * NPJ;
    float d0 = row[0];
    float4 B0 = *(const float4*)(row + 4);
    float4 B1 = *(const float4*)(row + 8);
    float4 B2 = *(const float4*)(row + 12);
    float4 B3 = *(const float4*)(row + 16);
    float4 C0 = *(const float4*)(row + 20);
    float4 C1 = *(const float4*)(row + 24);
    float4 C2 = *(const float4*)(row + 28);
    float4 C3 = *(const float4*)(row + 32);
    float dte = 1.f + exp2f(fmaf(d0, wl, bl));
    float du = dte * uv;
    float Bv[16] = {B0.x, B0.y, B0.z, B0.w, B1.x, B1.y, B1.z, B1.w,
                    B2.x, B2.y, B2.z, B2.w, B3.x, B3.y, B3.z, B3.w};
    float Cv[16] = {C0.x, C0.y, C0.z, C0.w, C1.x, C1.y, C1.z, C1.w,
                    C2.x, C2.y, C2.z, C2.w, C3.x, C3.y, C3.z, C3.w};
    float y = Dd * uv;
#pragma unroll
    for (int s = 0; s < 16; ++s) {
      float a = exp2f(A2[s] * dte);
      h[s] = fmaf(a, h[s], Bv[s] * du);
      y = fmaf(h[s], Cv[s], y);
    }
    unsigned short hh = f2bf_rn(y);
    char* q = yb + (size_t)l * (DI_N * 4);
    *(unsigned short*)q = hh;
    *(unsigned short*)(q + 16) = f2bf_rn(y - bf2f(hh));
  }
}

// ---------------------------------------------------------------------------
extern "C" void kernel_launch(void* const* d_in, const int* in_sizes, int n_in,
                              void* d_out, int out_size, void* d_ws, size_t ws_size,
                              hipStream_t stream) {
  const float* x          = (const float*)d_in[0];
  const float* in_proj_w  = (const float*)d_in[1];
  const float* conv_w     = (const float*)d_in[2];
  const float* conv_b     = (const float*)d_in[3];
  const float* x_proj_w   = (const float*)d_in[4];
  const float* dt_proj_w  = (const float*)d_in[5];
  const float* dt_proj_b  = (const float*)d_in[6];
  const float* A_log      = (const float*)d_in[7];
  const float* Dp         = (const float*)d_in[8];
  const float* out_proj_w = (const float*)d_in[9];
  float* out = (float*)d_out;

  char* ws = (char*)d_ws;
  float* xz = (float*)ws;                                  // [0, 67.11MB)
  float* u2 = (float*)(ws + (size_t)NTOK * 2 * DI_N * 4);  // [67.11, 100.66)

  // packed x / in_proj_w live in the u2 region (dead until conv_silu)
  char* x_pk  = (char*)u2;                                 // 16.78MB
  char* w1_pk = x_pk + (size_t)NTOK * DM_N * 4;            // 16.78MB

  // xz region reuse after conv_silu (all offsets within [0, 67.11MB))
  char*  y_pk   = ws;                                      // 33.55MB
  float* carryH = (float*)(ws + 33554432);                 // 8.39MB
  float* carryP = (float*)(ws + 41943040);                 // 8.39MB
  char*  w2_pk  = ws + 50331648;                           // 8.39MB
  float* xpart  = (float*)(ws + 58720256);                 // 4.72MB (8*4096*36*4)
  float* proj36 = (float*)(ws + 63438848);                 // 0.59MB (4096*36*4)

  // 1) split+pack x and in_proj_w
  {
    int n8 = NTOK * DM_N / 8;  // 524288
    split_pack_kernel<<<n8 / 256, 256, 0, stream>>>(x, (uint32_t*)x_pk, n8);
    split_pack_kernel<<<n8 / 256, 256, 0, stream>>>(in_proj_w, (uint32_t*)w1_pk, n8);
  }
  // 2) xz = x @ in_proj_w.T : M=4096 N=4096 K=1024 (K4=4096B), grid 1024
  gemm_pk_nt<<<1024, 256, 0, stream>>>(x_pk, w1_pk, xz, 2 * DI_N, DM_N * 4, 32);
  // 3) conv + silu
  {
    int nblk = (int)(((size_t)NTOK * DI_N + 255) / 256);
    conv_silu_kernel<<<nblk, 256, 0, stream>>>(xz, conv_w, conv_b, u2);
  }
  // 4) split+pack out_proj_w
  {
    int n8 = DM_N * DI_N / 8;  // 262144
    split_pack_kernel<<<n8 / 256, 256, 0, stream>>>(out_proj_w, (uint32_t*)w2_pk, n8);
  }
  // 5) proj36 = u2 @ x_proj_w.T  (2-stage K-split, padded rows)
  {
    xproj_part_kernel<<<(NTOK / 16) * XKC, 256, 0, stream>>>(u2, x_proj_w, xpart);
    xproj_reduce_kernel<<<(NTOK * NPJ) / 256, 256, 0, stream>>>(xpart, proj36);
  }
  // 6) chunked selective scan -> packed y
  {
    int nblk = (B_N * DI_N * NC) / 256;  // 512
    scan_pass1_kernel<<<nblk, 256, 0, stream>>>(u2, proj36, dt_proj_w, dt_proj_b,
                                                A_log, carryH, carryP);
    scan_fixup_kernel<<<(B_N * DI_N * DS_N) / 256, 256, 0, stream>>>(carryH, carryP);
    scan_pass2_kernel<<<nblk, 256, 0, stream>>>(u2, proj36, dt_proj_w, dt_proj_b,
                                                A_log, Dp, carryH, y_pk);
  }
  // 7) out = y @ out_proj_w.T : M=4096 N=1024 K=2048 (K4=8192B), grid 256
  gemm_pk_nt<<<256, 256, 0, stream>>>(y_pk, w2_pk, out, DM_N, DI_N * 4, 8);
}

// Round 7
// 369.808 us; speedup vs baseline: 4.4520x; 1.1741x over previous
//
#include <hip/hip_runtime.h>
#include <hip/hip_bf16.h>
#include <cstddef>
#include <cstdint>

#define B_N 2
#define L_N 2048
#define DM_N 1024
#define DS_N 16
#define DI_N 2048
#define NTOK (B_N * L_N)   // 4096
#define NPROJ 33           // 2*DS+1
#define NPJ 36             // padded proj row: d0@0, B@4..19, C@20..35
#define NC 64              // scan chunks
#define CL (L_N / NC)      // 32 steps per chunk
#define XKC 8              // xproj K-split
#define XKCL (DI_N / XKC)  // 256

typedef __attribute__((ext_vector_type(8))) short short8v;
typedef __attribute__((ext_vector_type(4))) float f32x4;
typedef __attribute__((address_space(1))) void av1;
typedef __attribute__((address_space(3))) void av3;

__device__ __forceinline__ void gload16(const void* g, void* l) {
  __builtin_amdgcn_global_load_lds((av1*)g, (av3*)l, 16, 0, 0);
}

__device__ __forceinline__ unsigned short f2bf_rn(float f) {
  uint32_t u = __float_as_uint(f);
  uint32_t r = (u + 0x7fffu + ((u >> 16) & 1u)) >> 16;
  return (unsigned short)r;
}
__device__ __forceinline__ float bf2f(unsigned short h) {
  return __uint_as_float((uint32_t)h << 16);
}

// ---------------------------------------------------------------------------
// Split fp32 -> packed [row][kgroup8][16B hi | 16B lo]. 8 elements/thread.
// ---------------------------------------------------------------------------
__global__ __launch_bounds__(256) void split_pack_kernel(
    const float* __restrict__ src, uint32_t* __restrict__ dst, int n8) {
  int idx = blockIdx.x * 256 + threadIdx.x;
  if (idx >= n8) return;
  const float4* s = (const float4*)src + (size_t)idx * 2;
  float4 v0 = s[0], v1 = s[1];
  float f[8] = {v0.x, v0.y, v0.z, v0.w, v1.x, v1.y, v1.z, v1.w};
  uint32_t hi[4], lo[4];
#pragma unroll
  for (int j = 0; j < 4; ++j) {
    unsigned short h0 = f2bf_rn(f[2 * j]);
    unsigned short h1 = f2bf_rn(f[2 * j + 1]);
    unsigned short l0 = f2bf_rn(f[2 * j] - bf2f(h0));
    unsigned short l1 = f2bf_rn(f[2 * j + 1] - bf2f(h1));
    hi[j] = (uint32_t)h0 | ((uint32_t)h1 << 16);
    lo[j] = (uint32_t)l0 | ((uint32_t)l1 << 16);
  }
  uint4* d = (uint4*)dst + (size_t)idx * 2;
  d[0] = make_uint4(hi[0], hi[1], hi[2], hi[3]);
  d[1] = make_uint4(lo[0], lo[1], lo[2], lo[3]);
}

// ---------------------------------------------------------------------------
// Packed split-bf16 NT GEMM (unchanged).
// ---------------------------------------------------------------------------
__global__ __launch_bounds__(256) void gemm_pk_nt(
    const char* __restrict__ Apk, const char* __restrict__ Bpk,
    float* __restrict__ C, int N, int K4, int gx) {
  __shared__ __align__(16) char lds[32768];
  const int tid = threadIdx.x;
  const int lane = tid & 63;
  const int wave = tid >> 6;

  const int nwg = gridDim.x;
  const int cpx = nwg >> 3;
  const int bid = blockIdx.x;
  const int wg = (bid & 7) * cpx + (bid >> 3);
  const int bx = wg % gx;
  const int by = wg / gx;
  const int m0 = by * 128, n0 = bx * 128;

  const int wr = wave >> 1, wc = wave & 1;

  const char* gbase = (wave & 2) ? Bpk : Apk;
  const int rowbase = ((wave & 2) ? n0 : m0) + (wave & 1) * 64;
  const int rloc = lane >> 3;
  const int sslot = (lane & 7) ^ rloc;
  const char* gsrc = gbase + (size_t)(rowbase + rloc) * K4 + sslot * 16;
  const size_t cstride = (size_t)8 * K4;
  char* ldst = lds + wave * 8192 + lane * 16;

  f32x4 acc[4][4] = {};
  const int fr = lane & 15;
  const int fg = lane >> 4;
  const int sA = ((fg * 2) ^ (fr & 7)) * 16;
  const int abase = (wr * 64 + fr) * 128 + sA;
  const int bbase = 16384 + (wc * 64 + fr) * 128 + sA;

  for (int kt4 = 0; kt4 < K4; kt4 += 128) {
#pragma unroll
    for (int c = 0; c < 8; ++c)
      gload16(gsrc + c * cstride + kt4, ldst + c * 1024);
    __syncthreads();

    short8v afh[4], afl[4], bfh[4], bfl[4];
#pragma unroll
    for (int m = 0; m < 4; ++m) {
      int a = abase + m * 2048;
      afh[m] = *(const short8v*)(lds + a);
      afl[m] = *(const short8v*)(lds + (a ^ 16));
    }
#pragma unroll
    for (int n = 0; n < 4; ++n) {
      int b = bbase + n * 2048;
      bfh[n] = *(const short8v*)(lds + b);
      bfl[n] = *(const short8v*)(lds + (b ^ 16));
    }
#pragma unroll
    for (int m = 0; m < 4; ++m) {
#pragma unroll
      for (int n = 0; n < 4; ++n) {
        asm("v_mfma_f32_16x16x32_bf16 %0, %1, %2, %0"
            : "+v"(acc[m][n]) : "v"(afh[m]), "v"(bfh[n]));
        asm("v_mfma_f32_16x16x32_bf16 %0, %1, %2, %0"
            : "+v"(acc[m][n]) : "v"(afh[m]), "v"(bfl[n]));
        asm("v_mfma_f32_16x16x32_bf16 %0, %1, %2, %0"
            : "+v"(acc[m][n]) : "v"(afl[m]), "v"(bfh[n]));
      }
    }
    __syncthreads();
  }

#pragma unroll
  for (int m = 0; m < 4; ++m) {
#pragma unroll
    for (int n = 0; n < 4; ++n) {
#pragma unroll
      for (int q = 0; q < 4; ++q) {
        int row = m0 + wr * 64 + m * 16 + fg * 4 + q;
        int col = n0 + wc * 64 + n * 16 + fr;
        C[(size_t)row * N + col] = acc[m][n][q];
      }
    }
  }
}

// ---------------------------------------------------------------------------
// Depthwise causal conv (DC=4) + bias, times silu(z). Reads xz = [u | z].
// ---------------------------------------------------------------------------
__global__ __launch_bounds__(256) void conv_silu_kernel(
    const float* __restrict__ xz, const float* __restrict__ cw,
    const float* __restrict__ cb, float* __restrict__ u2) {
  size_t idx = (size_t)blockIdx.x * 256 + threadIdx.x;
  if (idx >= (size_t)NTOK * DI_N) return;
  int i = (int)(idx & (DI_N - 1));
  int n = (int)(idx >> 11);
  int l = n & (L_N - 1);
  const float* base = xz + (size_t)n * (2 * DI_N) + i;
  const float4 w = *(const float4*)&cw[i * 4];
  float acc = fmaf(w.w, base[0], cb[i]);
  if (l >= 1) acc = fmaf(w.z, base[-(ptrdiff_t)(2 * DI_N)], acc);
  if (l >= 2) acc = fmaf(w.y, base[-(ptrdiff_t)(4 * DI_N)], acc);
  if (l >= 3) acc = fmaf(w.x, base[-(ptrdiff_t)(6 * DI_N)], acc);
  float z = base[DI_N];
  float sil = z / (1.f + __expf(-z));
  u2[(size_t)n * DI_N + i] = acc * sil;
}

// ---------------------------------------------------------------------------
// xproj stage 1: partials into padded 36-wide rows (d0@0, B@4..19, C@20..35).
// ---------------------------------------------------------------------------
__global__ __launch_bounds__(256) void xproj_part_kernel(
    const float* __restrict__ u2, const float* __restrict__ xw,
    float* __restrict__ part) {
  __shared__ float uS[16][257];
  __shared__ float wS[33][257];
  const int tid = threadIdx.x;
  const int kc = blockIdx.x & (XKC - 1);
  const int rb = blockIdx.x >> 3;
  const int row0 = rb * 16;
  const int k0 = kc * XKCL;

#pragma unroll
  for (int it = 0; it < 4; ++it) {
    int slot = tid + it * 256;
    int r = slot >> 6;
    int kq = (slot & 63) << 2;
    float4 v = *(const float4*)&u2[(size_t)(row0 + r) * DI_N + k0 + kq];
    uS[r][kq] = v.x; uS[r][kq + 1] = v.y;
    uS[r][kq + 2] = v.z; uS[r][kq + 3] = v.w;
  }
#pragma unroll
  for (int it = 0; it < 9; ++it) {
    int slot = tid + it * 256;
    if (slot < 33 * 64) {
      int c = slot >> 6;
      int kq = (slot & 63) << 2;
      float4 v = *(const float4*)&xw[(size_t)c * DI_N + k0 + kq];
      wS[c][kq] = v.x; wS[c][kq + 1] = v.y;
      wS[c][kq + 2] = v.z; wS[c][kq + 3] = v.w;
    }
  }
  __syncthreads();

  const int r = tid & 15;
  const int cg = tid >> 4;
  const int c0 = cg * 3;
  const int rc0 = c0 > 32 ? 32 : c0;
  const int rc1 = c0 + 1 > 32 ? 32 : c0 + 1;
  const int rc2 = c0 + 2 > 32 ? 32 : c0 + 2;
  float a0 = 0.f, a1 = 0.f, a2 = 0.f;
#pragma unroll 4
  for (int k = 0; k < XKCL; ++k) {
    float uv = uS[r][k];
    a0 = fmaf(uv, wS[rc0][k], a0);
    a1 = fmaf(uv, wS[rc1][k], a1);
    a2 = fmaf(uv, wS[rc2][k], a2);
  }
  size_t base = (size_t)kc * (NTOK * NPJ) + (size_t)(row0 + r) * NPJ;
  if (c0 < NPROJ)     part[base + (c0 == 0 ? 0 : c0 + 3)] = a0;
  if (c0 + 1 < NPROJ) part[base + c0 + 4] = a1;
  if (c0 + 2 < NPROJ) part[base + c0 + 5] = a2;
}

// ---------------------------------------------------------------------------
// xproj stage 2: proj36 = sum over the 8 K-chunk partials (fixed order).
// ---------------------------------------------------------------------------
__global__ __launch_bounds__(256) void xproj_reduce_kernel(
    const float* __restrict__ part, float* __restrict__ proj) {
  int idx = blockIdx.x * 256 + threadIdx.x;  // < NTOK*NPJ = 147456
  float s = 0.f;
#pragma unroll
  for (int kc = 0; kc < XKC; ++kc)
    s += part[(size_t)kc * (NTOK * NPJ) + idx];
  proj[idx] = s;
}

// ---------------------------------------------------------------------------
// Scan pass 1: block = (b, chunk, 256 i-channels). proj chunk staged in LDS.
// Emits chunk-end h[16] and sdte = sum(dte) (P recomputed in fixup).
// ---------------------------------------------------------------------------
__global__ __launch_bounds__(256) void scan_pass1_kernel(
    const float* __restrict__ u2, const float* __restrict__ pj,
    const float* __restrict__ dtw, const float* __restrict__ dtb,
    const float* __restrict__ A_log,
    float* __restrict__ carryH, float* __restrict__ sdteO) {
  __shared__ float pS[CL][20];
  const int tid = threadIdx.x;
  const int bid = blockIdx.x;
  const int ib = bid & 7;
  const int c = (bid >> 3) & (NC - 1);
  const int b = bid >> 9;
  const int i = ib * 256 + tid;
  const int l0 = c * CL;
  const float LOG2E = 1.4426950408889634f;

  // stage d0 + B slots (0..19) for the chunk: CL*5 = 160 float4
  if (tid < CL * 5) {
    int row = tid / 5, j = tid % 5;
    float4 v = *(const float4*)&pj[((size_t)b * L_N + l0 + row) * NPJ + j * 4];
    *(float4*)&pS[row][j * 4] = v;
  }

  float A2[16];
#pragma unroll
  for (int q = 0; q < 4; ++q) {
    float4 v = *(const float4*)&A_log[i * DS_N + q * 4];
    A2[q * 4 + 0] = -__expf(v.x) * LOG2E;
    A2[q * 4 + 1] = -__expf(v.y) * LOG2E;
    A2[q * 4 + 2] = -__expf(v.z) * LOG2E;
    A2[q * 4 + 3] = -__expf(v.w) * LOG2E;
  }
  const float wl = dtw[i] * LOG2E;
  const float bl = dtb[i] * LOG2E;
  const float* un = u2 + ((size_t)b * L_N + l0) * DI_N + i;
  __syncthreads();

  float h[16] = {};
  float sdte = 0.f;
  float ucur = un[0];
#pragma unroll 2
  for (int l = 0; l < CL; ++l) {
    float unext = (l + 1 < CL) ? un[(size_t)(l + 1) * DI_N] : 0.f;
    float d0 = pS[l][0];
    float4 B0 = *(const float4*)&pS[l][4];
    float4 B1 = *(const float4*)&pS[l][8];
    float4 B2 = *(const float4*)&pS[l][12];
    float4 B3 = *(const float4*)&pS[l][16];
    float dte = 1.f + exp2f(fmaf(d0, wl, bl));
    float du = dte * ucur;
    sdte += dte;
    float Bv[16] = {B0.x, B0.y, B0.z, B0.w, B1.x, B1.y, B1.z, B1.w,
                    B2.x, B2.y, B2.z, B2.w, B3.x, B3.y, B3.z, B3.w};
#pragma unroll
    for (int s = 0; s < 16; ++s) {
      float a = exp2f(A2[s] * dte);
      h[s] = fmaf(a, h[s], Bv[s] * du);
    }
    ucur = unext;
  }
  size_t cbase = (((size_t)c * B_N + b) * DI_N + i) * DS_N;
#pragma unroll
  for (int q = 0; q < 4; ++q) {
    float4 hv = {h[q * 4], h[q * 4 + 1], h[q * 4 + 2], h[q * 4 + 3]};
    *(float4*)&carryH[cbase + q * 4] = hv;
  }
  sdteO[((size_t)c * B_N + b) * DI_N + i] = sdte;
}

// ---------------------------------------------------------------------------
// Fixup: chain chunk carries; carryH[c] <- incoming state for chunk c.
// P recomputed as 2^(A2*sdte). Thread q = (b, i, s).
// ---------------------------------------------------------------------------
__global__ __launch_bounds__(256) void scan_fixup_kernel(
    float* __restrict__ carryH, const float* __restrict__ sdte,
    const float* __restrict__ A_log) {
  const int q = blockIdx.x * 256 + threadIdx.x;  // < B*DI*DS = 65536
  const int s = q & 15;
  const int i = (q >> 4) & (DI_N - 1);
  const float LOG2E = 1.4426950408889634f;
  const float A2 = -__expf(A_log[i * DS_N + s]) * LOG2E;
  float h = 0.f;
#pragma unroll 8
  for (int c = 0; c < NC; ++c) {
    size_t idx = (size_t)c * (B_N * DI_N * DS_N) + q;
    float Hc = carryH[idx];
    float sd = sdte[(size_t)c * (B_N * DI_N) + (q >> 4)];
    carryH[idx] = h;
    h = fmaf(exp2f(A2 * sd), h, Hc);
  }
}

// ---------------------------------------------------------------------------
// Scan pass 2: block = (b, chunk, 256 i); proj chunk in LDS; packed y out.
// ---------------------------------------------------------------------------
__global__ __launch_bounds__(256) void scan_pass2_kernel(
    const float* __restrict__ u2, const float* __restrict__ pj,
    const float* __restrict__ dtw, const float* __restrict__ dtb,
    const float* __restrict__ A_log, const float* __restrict__ Dp,
    const float* __restrict__ carryH, char* __restrict__ ypk) {
  __shared__ float pS[CL][36];
  const int tid = threadIdx.x;
  const int bid = blockIdx.x;
  const int ib = bid & 7;
  const int c = (bid >> 3) & (NC - 1);
  const int b = bid >> 9;
  const int i = ib * 256 + tid;
  const int l0 = c * CL;
  const float LOG2E = 1.4426950408889634f;

  // stage full rows (36 floats): CL*9 = 288 float4
#pragma unroll
  for (int it = 0; it < 2; ++it) {
    int slot = tid + it * 256;
    if (slot < CL * 9) {
      int row = slot / 9, j = slot % 9;
      float4 v = *(const float4*)&pj[((size_t)b * L_N + l0 + row) * NPJ + j * 4];
      *(float4*)&pS[row][j * 4] = v;
    }
  }

  float A2[16];
#pragma unroll
  for (int q = 0; q < 4; ++q) {
    float4 v = *(const float4*)&A_log[i * DS_N + q * 4];
    A2[q * 4 + 0] = -__expf(v.x) * LOG2E;
    A2[q * 4 + 1] = -__expf(v.y) * LOG2E;
    A2[q * 4 + 2] = -__expf(v.z) * LOG2E;
    A2[q * 4 + 3] = -__expf(v.w) * LOG2E;
  }
  const float wl = dtw[i] * LOG2E;
  const float bl = dtb[i] * LOG2E;
  const float Dd = Dp[i];

  float h[16];
  size_t cbase = (((size_t)c * B_N + b) * DI_N + i) * DS_N;
#pragma unroll
  for (int q = 0; q < 4; ++q) {
    float4 hv = *(const float4*)&carryH[cbase + q * 4];
    h[q * 4] = hv.x; h[q * 4 + 1] = hv.y;
    h[q * 4 + 2] = hv.z; h[q * 4 + 3] = hv.w;
  }

  const float* un = u2 + ((size_t)b * L_N + l0) * DI_N + i;
  char* yb = ypk + ((size_t)b * L_N + l0) * (DI_N * 4) + (i >> 3) * 32 + (i & 7) * 2;
  __syncthreads();

  float ucur = un[0];
#pragma unroll 2
  for (int l = 0; l < CL; ++l) {
    float unext = (l + 1 < CL) ? un[(size_t)(l + 1) * DI_N] : 0.f;
    float d0 = pS[l][0];
    float4 B0 = *(const float4*)&pS[l][4];
    float4 B1 = *(const float4*)&pS[l][8];
    float4 B2 = *(const float4*)&pS[l][12];
    float4 B3 = *(const float4*)&pS[l][16];
    float4 C0 = *(const float4*)&pS[l][20];
    float4 C1 = *(const float4*)&pS[l][24];
    float4 C2 = *(const float4*)&pS[l][28];
    float4 C3 = *(const float4*)&pS[l][32];
    float dte = 1.f + exp2f(fmaf(d0, wl, bl));
    float du = dte * ucur;
    float Bv[16] = {B0.x, B0.y, B0.z, B0.w, B1.x, B1.y, B1.z, B1.w,
                    B2.x, B2.y, B2.z, B2.w, B3.x, B3.y, B3.z, B3.w};
    float Cv[16] = {C0.x, C0.y, C0.z, C0.w, C1.x, C1.y, C1.z, C1.w,
                    C2.x, C2.y, C2.z, C2.w, C3.x, C3.y, C3.z, C3.w};
    float y = Dd * ucur;
#pragma unroll
    for (int s = 0; s < 16; ++s) {
      float a = exp2f(A2[s] * dte);
      h[s] = fmaf(a, h[s], Bv[s] * du);
      y = fmaf(h[s], Cv[s], y);
    }
    unsigned short hh = f2bf_rn(y);
    char* q = yb + (size_t)l * (DI_N * 4);
    *(unsigned short*)q = hh;
    *(unsigned short*)(q + 16) = f2bf_rn(y - bf2f(hh));
    ucur = unext;
  }
}

// ---------------------------------------------------------------------------
extern "C" void kernel_launch(void* const* d_in, const int* in_sizes, int n_in,
                              void* d_out, int out_size, void* d_ws, size_t ws_size,
                              hipStream_t stream) {
  const float* x          = (const float*)d_in[0];
  const float* in_proj_w  = (const float*)d_in[1];
  const float* conv_w     = (const float*)d_in[2];
  const float* conv_b     = (const float*)d_in[3];
  const float* x_proj_w   = (const float*)d_in[4];
  const float* dt_proj_w  = (const float*)d_in[5];
  const float* dt_proj_b  = (const float*)d_in[6];
  const float* A_log      = (const float*)d_in[7];
  const float* Dp         = (const float*)d_in[8];
  const float* out_proj_w = (const float*)d_in[9];
  float* out = (float*)d_out;

  char* ws = (char*)d_ws;
  float* xz = (float*)ws;                                  // [0, 67.11MB)
  float* u2 = (float*)(ws + (size_t)NTOK * 2 * DI_N * 4);  // [67.11, 100.66)

  // packed x / in_proj_w live in the u2 region (dead until conv_silu)
  char* x_pk  = (char*)u2;                                 // 16.78MB
  char* w1_pk = x_pk + (size_t)NTOK * DM_N * 4;            // 16.78MB

  // xz region reuse after conv_silu (all within [0, 67.11MB))
  char*  y_pk   = ws;                                      // 33.55MB
  float* carryH = (float*)(ws + 33554432);                 // 16.78MB (64*2*2048*16*4)
  float* sdte   = (float*)(ws + 50331648);                 // 1.05MB  (64*2*2048*4)
  char*  w2_pk  = ws + 51380224;                           // 8.39MB
  float* xpart  = (float*)(ws + 59768832);                 // 4.72MB (8*4096*36*4)
  float* proj36 = (float*)(ws + 64487424);                 // 0.59MB (4096*36*4)

  // 1) split+pack x and in_proj_w
  {
    int n8 = NTOK * DM_N / 8;  // 524288
    split_pack_kernel<<<n8 / 256, 256, 0, stream>>>(x, (uint32_t*)x_pk, n8);
    split_pack_kernel<<<n8 / 256, 256, 0, stream>>>(in_proj_w, (uint32_t*)w1_pk, n8);
  }
  // 2) xz = x @ in_proj_w.T : M=4096 N=4096 K=1024 (K4=4096B), grid 1024
  gemm_pk_nt<<<1024, 256, 0, stream>>>(x_pk, w1_pk, xz, 2 * DI_N, DM_N * 4, 32);
  // 3) conv + silu
  {
    int nblk = (int)(((size_t)NTOK * DI_N + 255) / 256);
    conv_silu_kernel<<<nblk, 256, 0, stream>>>(xz, conv_w, conv_b, u2);
  }
  // 4) split+pack out_proj_w
  {
    int n8 = DM_N * DI_N / 8;  // 262144
    split_pack_kernel<<<n8 / 256, 256, 0, stream>>>(out_proj_w, (uint32_t*)w2_pk, n8);
  }
  // 5) proj36 = u2 @ x_proj_w.T  (2-stage K-split, padded rows)
  {
    xproj_part_kernel<<<(NTOK / 16) * XKC, 256, 0, stream>>>(u2, x_proj_w, xpart);
    xproj_reduce_kernel<<<(NTOK * NPJ) / 256, 256, 0, stream>>>(xpart, proj36);
  }
  // 6) chunked selective scan -> packed y
  {
    int nblk = B_N * NC * (DI_N / 256);  // 1024
    scan_pass1_kernel<<<nblk, 256, 0, stream>>>(u2, proj36, dt_proj_w, dt_proj_b,
                                                A_log, carryH, sdte);
    scan_fixup_kernel<<<(B_N * DI_N * DS_N) / 256, 256, 0, stream>>>(carryH, sdte,
                                                                     A_log);
    scan_pass2_kernel<<<nblk, 256, 0, stream>>>(u2, proj36, dt_proj_w, dt_proj_b,
                                                A_log, Dp, carryH, y_pk);
  }
  // 7) out = y @ out_proj_w.T : M=4096 N=1024 K=2048 (K4=8192B), grid 256
  gemm_pk_nt<<<256, 256, 0, stream>>>(y_pk, w2_pk, out, DM_N, DI_N * 4, 8);
}